// Round 5
// baseline (12507.374 us; speedup 1.0000x reference)
//
#include <hip/hip_runtime.h>
#include <hip/hip_bf16.h>
#include <cstdint>
#include <cstddef>

#define BB   256   // batch
#define SS   512   // encoder seq len
#define RDIM 128   // embed dim
#define HH   512   // hidden
#define TT   96    // decoder steps

typedef unsigned int u32;
typedef _Float16 f16;
typedef __attribute__((ext_vector_type(8))) _Float16 f16x8;
typedef __attribute__((ext_vector_type(4))) float f32x4;

__device__ __forceinline__ float sigm(float x){ return 1.0f/(1.0f+__expf(-x)); }
__device__ __forceinline__ float tanh_f(float x){ return 1.0f - 2.0f/(__expf(2.0f*x)+1.0f); }
__device__ __forceinline__ float2 cvt2(u32 x){
  union { u32 u; f16 h[2]; } t; t.u = x;
  return make_float2((float)t.h[0], (float)t.h[1]);
}

__device__ __forceinline__ void fence_rel(){ __builtin_amdgcn_fence(__ATOMIC_RELEASE, "agent"); }
__device__ __forceinline__ void fence_acq(){ __builtin_amdgcn_fence(__ATOMIC_ACQUIRE, "agent"); }

// L1-bypassing dword load (agent-scope relaxed atomic -> sc1 flag, reads L2/IC).
__device__ __forceinline__ u32 ld_sc0(const u32* p){
  return __hip_atomic_load((u32*)p, __ATOMIC_RELAXED, __HIP_MEMORY_SCOPE_AGENT);
}
__device__ __forceinline__ uint4 ld4_sc0(const u32* p){
  return make_uint4(ld_sc0(p), ld_sc0(p+1), ld_sc0(p+2), ld_sc0(p+3));
}

#define SPIN_CAP 50000   // escape hatch; legit waits are << this

// 32-block domain barrier. slow=1: agent fences (cross-XCD correct, proven R3).
// slow=0: fence-free (valid when all 32 blocks share an XCD; data visibility
// via write-through L1 -> shared L2 + sc0 consumer loads; counter is IC-coherent).
__device__ __forceinline__ void bar32(u32* ctr, u32 target, int slow){
  __syncthreads();                 // compiler emits s_waitcnt vmcnt(0) before s_barrier
  if(threadIdx.x == 0){
    if(slow) fence_rel();
    __hip_atomic_fetch_add(ctr, 1u, __ATOMIC_RELAXED, __HIP_MEMORY_SCOPE_AGENT);
    int spins = 0;
    while(__hip_atomic_load(ctr, __ATOMIC_RELAXED, __HIP_MEMORY_SCOPE_AGENT) < target){
      __builtin_amdgcn_s_sleep(8);
      if(++spins > SPIN_CAP) break;
    }
    if(slow) fence_acq();
  }
  __syncthreads();
}

// Fence-free-mode validity probe: 2 rounds of {plain-store canary, fast barrier,
// sc0 peer-read}. Any stale read -> domain flag=1 -> caller uses slow barriers.
// Flag traffic uses atomics only (coherent regardless of placement).
// Consumes generations 1..4 of ctr; caller continues from gen=4.
__device__ __forceinline__ int probe32(u32* ctr, u32* can, u32* flg,
                                       int id, int g, int tid){
  __shared__ u32 okf;
  u32 gen = 0;
  #pragma unroll
  for(int r=0;r<2;r++){
    u32 tag = r ? 0x5A5A0000u : 0xA5A50000u;
    if(tid==0) can[(size_t)id*64 + r] = tag + (u32)id;   // plain store -> L2
    ++gen; bar32(ctr, 32u*gen, 0);
    if(tid==0) okf = 1u;
    __syncthreads();
    if(tid < 32){
      int mid = g + 8*tid;                                // domain members
      u32 v = ld_sc0(can + (size_t)mid*64 + r);
      if(v != tag + (u32)mid) okf = 0u;                   // benign race (1->0)
    }
    __syncthreads();
    if(tid==0 && okf==0u)
      __hip_atomic_store(flg, 1u, __ATOMIC_RELAXED, __HIP_MEMORY_SCOPE_AGENT);
    ++gen; bar32(ctr, 32u*gen, 0);
  }
  return (int)__hip_atomic_load(flg, __ATOMIC_RELAXED, __HIP_MEMORY_SCOPE_AGENT);
}

// ---------------------------------------------------------------------------
// Prep kernels (unchanged, r0-verified)
// ---------------------------------------------------------------------------

__global__ void prep_uv(const float* __restrict__ Wih, const float* __restrict__ embW,
                        const float* __restrict__ embB, const float* __restrict__ bih,
                        const float* __restrict__ bhh, const float* __restrict__ dbih,
                        const float* __restrict__ dbhh,
                        float* __restrict__ u, float* __restrict__ v, float* __restrict__ bd){
  int n = blockIdx.x*256 + threadIdx.x;   // 0..2047
  const float* row = Wih + (size_t)n*RDIM;
  float su = 0.f, sv = 0.f;
  for(int r=0;r<RDIM;r++){ float w = row[r]; su += w*embW[r]; sv += w*embB[r]; }
  u[n] = su;
  v[n] = sv + bih[n] + bhh[n];
  bd[n] = dbih[n] + dbhh[n];
}

__global__ void prep_wqk(const float* __restrict__ Wq, const float* __restrict__ Wk,
                         float* __restrict__ Wqk_t){
  __shared__ float wkc[HH];
  int n = blockIdx.x;
  for(int i=threadIdx.x;i<HH;i+=256) wkc[i] = Wk[(size_t)i*HH + n];
  __syncthreads();
  for(int a=threadIdx.x;a<HH;a+=256){
    float s = 0.f;
    for(int hp=0;hp<HH;hp++) s += Wq[(size_t)hp*HH + a]*wkc[hp];
    Wqk_t[(size_t)n*HH + a] = s;
  }
}

__global__ void prep_bqk(const float* __restrict__ bq, const float* __restrict__ Wk,
                         float* __restrict__ bqk){
  int n = blockIdx.x*256 + threadIdx.x;
  float s = 0.f;
  for(int hp=0;hp<HH;hp++) s += bq[hp]*Wk[(size_t)hp*HH + n];
  bqk[n] = s;
}

__global__ void prep_wenc(const float* __restrict__ Whh, const float* __restrict__ u,
                          const float* __restrict__ v, f16* __restrict__ Wfm){
  int nt = blockIdx.x, kk = blockIdx.y, L = threadIdx.x;
  int jb = nt>>2, ct = nt&3;
  int n = ct*HH + jb*16 + (L&15);
  int q = L>>4;
  union { f16 h[8]; uint4 u4; } z;
  if(kk < 16){
    const float* src = Whh + (size_t)n*HH + kk*32 + q*8;
    #pragma unroll
    for(int j=0;j<8;j++) z.h[j] = (f16)src[j];
  } else {
    #pragma unroll
    for(int j=0;j<8;j++) z.h[j] = (f16)0.0f;
    if(q==0){ z.h[0] = (f16)u[n]; z.h[1] = (f16)v[n]; }
  }
  *(uint4*)(Wfm + (((size_t)nt*17 + kk)*64 + L)*8) = z.u4;
}

__global__ void prep_wdec(const float* __restrict__ dWih, const float* __restrict__ dWhh,
                          const float* __restrict__ bd, f16* __restrict__ Wfm){
  int nt = blockIdx.x, kk = blockIdx.y, L = threadIdx.x;
  int jb = nt>>3, ct = nt&7;
  int n = (ct>>1)*HH + jb*32 + (ct&1)*16 + (L&15);
  int q = L>>4;
  union { f16 h[8]; uint4 u4; } z;
  if(kk < 32){
    int k0 = kk*32 + q*8;
    #pragma unroll
    for(int j=0;j<8;j++){
      float wv = dWih[(size_t)n*1024 + k0 + j];
      if(k0 + j < HH) wv += dWhh[(size_t)n*HH + k0 + j];
      z.h[j] = (f16)wv;
    }
  } else {
    #pragma unroll
    for(int j=0;j<8;j++) z.h[j] = (f16)0.0f;
    if(q==0) z.h[0] = (f16)bd[n];
  }
  *(uint4*)(Wfm + (((size_t)nt*33 + kk)*64 + L)*8) = z.u4;
}

__global__ void prep_wqfm(const float* __restrict__ Wqk_t, const float* __restrict__ bqk,
                          f16* __restrict__ Wfm){
  int nt = blockIdx.x, kk = blockIdx.y, L = threadIdx.x;
  int n = nt*16 + (L&15);
  int q = L>>4;
  union { f16 h[8]; uint4 u4; } z;
  if(kk < 16){
    const float* src = Wqk_t + (size_t)n*HH + kk*32 + q*8;
    #pragma unroll
    for(int j=0;j<8;j++) z.h[j] = (f16)src[j];
  } else {
    #pragma unroll
    for(int j=0;j<8;j++) z.h[j] = (f16)0.0f;
    if(q==0) z.h[0] = (f16)bqk[n];
  }
  *(uint4*)(Wfm + (((size_t)nt*17 + kk)*64 + L)*8) = z.u4;
}

// ---------------------------------------------------------------------------
// r0-VERIFIED standalone step kernels (fallback path)
// ---------------------------------------------------------------------------
#define STR 552   // LDS row stride in f16 (544 data + 8 pad)

__launch_bounds__(256)
__global__ void enc_step(const f16* __restrict__ hin, f16* __restrict__ hout,
                         float* __restrict__ cbuf, const f16* __restrict__ Wfm,
                         const float* __restrict__ einp, f16* __restrict__ hx, int t){
  __shared__ f16 hsm[32*STR];
  __shared__ float gt[64][33];
  const int tid = threadIdx.x;
  const int b0 = blockIdx.x*32, jb = blockIdx.y;

  {
    int row = tid>>3, c0 = tid&7;
    const uint4* src = (const uint4*)(hin + (size_t)(b0+row)*HH);
    uint4* drow = (uint4*)(hsm + row*STR);
    #pragma unroll
    for(int i=0;i<8;i++) drow[c0 + 8*i] = src[c0 + 8*i];
  }
  if(tid < 128){
    int row = tid>>2, pc = tid&3;
    union { f16 h[8]; uint4 u4; } z;
    #pragma unroll
    for(int j=0;j<8;j++) z.h[j] = (f16)0.0f;
    if(pc==0){ z.h[0] = (f16)einp[(size_t)(b0+row)*SS + t]; z.h[1] = (f16)1.0f; }
    *((uint4*)(hsm + row*STR) + 64 + pc) = z.u4;
  }
  __syncthreads();

  const int lane = tid & 63, w = tid>>6;
  const int rt = w & 1, ctb = (w>>1)*2;
  const int m = lane & 15, q = lane>>4;
  f32x4 acc0 = {0.f,0.f,0.f,0.f}, acc1 = {0.f,0.f,0.f,0.f};
  const f16* arow = hsm + (rt*16 + m)*STR + q*8;
  const f16x8* bp0 = (const f16x8*)Wfm + ((size_t)(jb*4+ctb  )*17)*64 + lane;
  const f16x8* bp1 = (const f16x8*)Wfm + ((size_t)(jb*4+ctb+1)*17)*64 + lane;
  #pragma unroll
  for(int kk=0;kk<17;kk++){
    f16x8 a  = *(const f16x8*)(arow + kk*32);
    f16x8 b0 = bp0[kk*64];
    f16x8 b1 = bp1[kk*64];
    acc0 = __builtin_amdgcn_mfma_f32_16x16x32_f16(a, b0, acc0, 0,0,0);
    acc1 = __builtin_amdgcn_mfma_f32_16x16x32_f16(a, b1, acc1, 0,0,0);
  }
  #pragma unroll
  for(int r=0;r<4;r++){
    gt[(ctb  )*16 + m][rt*16 + q*4 + r] = acc0[r];   // C/D: col=lane&15, row=4q+r
    gt[(ctb+1)*16 + m][rt*16 + q*4 + r] = acc1[r];
  }
  __syncthreads();

  #pragma unroll
  for(int qq=0;qq<2;qq++){
    int idx = tid + qq*256;
    int jc = idx & 15, rr = idx >> 4;
    float gi = gt[jc][rr];
    float gf = gt[16+jc][rr];
    float gg = gt[32+jc][rr];
    float go = gt[48+jc][rr];
    int b = b0 + rr, j = jb*16 + jc;
    size_t ci = (size_t)b*HH + j;
    float cv = sigm(gf)*cbuf[ci] + sigm(gi)*tanh_f(gg);
    cbuf[ci] = cv;
    float hv = sigm(go)*tanh_f(cv);
    hout[ci] = (f16)hv;
    hx[((size_t)b*SS + t)*HH + j] = (f16)hv;
  }
}

__launch_bounds__(256)
__global__ void qproj(const f16* __restrict__ hin, const f16* __restrict__ Wfm,
                      float* __restrict__ qt){
  __shared__ f16 hsm[32*STR];
  const int tid = threadIdx.x;
  const int b0 = blockIdx.x*32, jb = blockIdx.y;
  {
    int row = tid>>3, c0 = tid&7;
    const uint4* src = (const uint4*)(hin + (size_t)(b0+row)*HH);
    uint4* drow = (uint4*)(hsm + row*STR);
    #pragma unroll
    for(int i=0;i<8;i++) drow[c0 + 8*i] = src[c0 + 8*i];
  }
  if(tid < 128){
    int row = tid>>2, pc = tid&3;
    union { f16 h[8]; uint4 u4; } z;
    #pragma unroll
    for(int j=0;j<8;j++) z.h[j] = (f16)0.0f;
    if(pc==0) z.h[0] = (f16)1.0f;
    *((uint4*)(hsm + row*STR) + 64 + pc) = z.u4;
  }
  __syncthreads();

  const int lane = tid & 63, w = tid>>6;
  const int rt = w & 1, ctb = (w>>1)*2;
  const int m = lane & 15, q = lane>>4;
  f32x4 acc0 = {0.f,0.f,0.f,0.f}, acc1 = {0.f,0.f,0.f,0.f};
  const f16* arow = hsm + (rt*16 + m)*STR + q*8;
  const f16x8* bp0 = (const f16x8*)Wfm + ((size_t)(jb*4+ctb  )*17)*64 + lane;
  const f16x8* bp1 = (const f16x8*)Wfm + ((size_t)(jb*4+ctb+1)*17)*64 + lane;
  #pragma unroll
  for(int kk=0;kk<17;kk++){
    f16x8 a  = *(const f16x8*)(arow + kk*32);
    f16x8 b0 = bp0[kk*64];
    f16x8 b1 = bp1[kk*64];
    acc0 = __builtin_amdgcn_mfma_f32_16x16x32_f16(a, b0, acc0, 0,0,0);
    acc1 = __builtin_amdgcn_mfma_f32_16x16x32_f16(a, b1, acc1, 0,0,0);
  }
  #pragma unroll
  for(int r=0;r<4;r++){
    int b = b0 + rt*16 + q*4 + r;
    qt[(size_t)b*HH + jb*64 + (ctb  )*16 + m] = acc0[r];
    qt[(size_t)b*HH + jb*64 + (ctb+1)*16 + m] = acc1[r];
  }
}

__launch_bounds__(256)
__global__ void attn(const float* __restrict__ qt, const f16* __restrict__ hx,
                     f16* __restrict__ ctx){
  __shared__ unsigned short xs[32][520];
  __shared__ float sc[32];
  const int b = blockIdx.x, tid = threadIdx.x;
  const int seg = tid & 7;
  const int sp  = tid >> 3;

  float qreg[64];
  {
    const float4* qv = (const float4*)(qt + (size_t)b*HH + seg*64);
    #pragma unroll
    for(int i=0;i<16;i++){
      float4 v4 = qv[i];
      qreg[i*4+0]=v4.x; qreg[i*4+1]=v4.y; qreg[i*4+2]=v4.z; qreg[i*4+3]=v4.w;
    }
  }

  float m = -1e30f, l = 0.f, a0 = 0.f, a1 = 0.f;
  const uint4* src = (const uint4*)(hx + (size_t)b*SS*HH);

  for(int tile=0; tile<16; ++tile){
    __syncthreads();
    const uint4* tsrc = src + (size_t)tile*2048;
    #pragma unroll
    for(int kk=0;kk<8;kk++){
      uint4 vv = tsrc[kk*256 + tid];
      int e  = (kk*256 + tid)*8;
      int ss = e >> 9, hh = e & 511;
      *(uint4*)&xs[ss][hh] = vv;
    }
    __syncthreads();

    float p = 0.f;
    const uint4* xrow = (const uint4*)&xs[sp][seg*64];
    #pragma unroll
    for(int i=0;i<8;i++){
      uint4 vv = xrow[i];
      float2 t0 = cvt2(vv.x), t1 = cvt2(vv.y), t2 = cvt2(vv.z), t3 = cvt2(vv.w);
      p = fmaf(qreg[i*8+0], t0.x, p);
      p = fmaf(qreg[i*8+1], t0.y, p);
      p = fmaf(qreg[i*8+2], t1.x, p);
      p = fmaf(qreg[i*8+3], t1.y, p);
      p = fmaf(qreg[i*8+4], t2.x, p);
      p = fmaf(qreg[i*8+5], t2.y, p);
      p = fmaf(qreg[i*8+6], t3.x, p);
      p = fmaf(qreg[i*8+7], t3.y, p);
    }
    p += __shfl_xor(p, 1);
    p += __shfl_xor(p, 2);
    p += __shfl_xor(p, 4);
    if(seg == 0) sc[sp] = p;
    __syncthreads();

    float tmax = -1e30f;
    #pragma unroll
    for(int s2=0;s2<32;s2++) tmax = fmaxf(tmax, sc[s2]);
    float mnew  = fmaxf(m, tmax);
    float alpha = __expf(m - mnew);
    a0 *= alpha; a1 *= alpha; l *= alpha;
    #pragma unroll 4
    for(int s2=0;s2<32;s2++){
      float pv = __expf(sc[s2] - mnew);
      l += pv;
      u32 xv = *(const u32*)&xs[s2][2*tid];
      float2 xf = cvt2(xv);
      a0 = fmaf(pv, xf.x, a0);
      a1 = fmaf(pv, xf.y, a1);
    }
    m = mnew;
  }
  float inv = 1.0f/l;
  union { u32 u; f16 h[2]; } pk;
  pk.h[0] = (f16)(a0*inv); pk.h[1] = (f16)(a1*inv);
  *(u32*)(ctx + (size_t)b*HH + 2*tid) = pk.u;
}

#define STRD 1064  // 1056 data + 8 pad (2128B)

__launch_bounds__(256)
__global__ void dec_step(const f16* __restrict__ hin, f16* __restrict__ hout,
                         float* __restrict__ cbuf, const f16* __restrict__ ctxv,
                         const f16* __restrict__ Wfm, f16* __restrict__ hdec, int t){
  __shared__ f16 hsm[16*STRD];
  __shared__ float gt[128][17];
  const int tid = threadIdx.x;
  const int b0 = blockIdx.x*16, jb = blockIdx.y;

  {
    int row = tid>>4, c0 = tid&15;
    const uint4* srch = (const uint4*)(hin  + (size_t)(b0+row)*HH);
    const uint4* srcc = (const uint4*)(ctxv + (size_t)(b0+row)*HH);
    uint4* drow = (uint4*)(hsm + row*STRD);
    #pragma unroll
    for(int i=0;i<8;i++){
      int c = c0 + 16*i;
      drow[c] = (c < 64) ? srch[c] : srcc[c-64];
    }
  }
  if(tid < 64){
    int row = tid>>2, pc = tid&3;
    union { f16 h[8]; uint4 u4; } z;
    #pragma unroll
    for(int j=0;j<8;j++) z.h[j] = (f16)0.0f;
    if(pc==0) z.h[0] = (f16)1.0f;
    *((uint4*)(hsm + row*STRD) + 128 + pc) = z.u4;
  }
  __syncthreads();

  const int lane = tid & 63, w = tid>>6;
  const int ctb = w*2;
  const int m = lane & 15, q = lane>>4;
  f32x4 acc0 = {0.f,0.f,0.f,0.f}, acc1 = {0.f,0.f,0.f,0.f};
  const f16* arow = hsm + m*STRD + q*8;
  const f16x8* bp0 = (const f16x8*)Wfm + ((size_t)(jb*8+ctb  )*33)*64 + lane;
  const f16x8* bp1 = (const f16x8*)Wfm + ((size_t)(jb*8+ctb+1)*33)*64 + lane;
  #pragma unroll
  for(int kk=0;kk<33;kk++){
    f16x8 a  = *(const f16x8*)(arow + kk*32);
    f16x8 b0 = bp0[kk*64];
    f16x8 b1 = bp1[kk*64];
    acc0 = __builtin_amdgcn_mfma_f32_16x16x32_f16(a, b0, acc0, 0,0,0);
    acc1 = __builtin_amdgcn_mfma_f32_16x16x32_f16(a, b1, acc1, 0,0,0);
  }
  #pragma unroll
  for(int r=0;r<4;r++){
    gt[(ctb  )*16 + m][q*4 + r] = acc0[r];
    gt[(ctb+1)*16 + m][q*4 + r] = acc1[r];
  }
  __syncthreads();

  #pragma unroll
  for(int qq=0;qq<2;qq++){
    int idx = tid + qq*256;
    int jc = idx & 31, rr = idx >> 5;    // jc 0..31, rr 0..15
    float gi = gt[jc][rr];
    float gf = gt[32+jc][rr];
    float gg = gt[64+jc][rr];
    float go = gt[96+jc][rr];
    int b = b0 + rr, j = jb*32 + jc;
    size_t ci = (size_t)b*HH + j;
    float cv = sigm(gf)*cbuf[ci] + sigm(gi)*tanh_f(gg);
    cbuf[ci] = cv;
    float hv = sigm(go)*tanh_f(cv);
    hout[ci] = (f16)hv;
    hdec[((size_t)t*BB + b)*HH + j] = (f16)hv;
  }
}

// ---------------------------------------------------------------------------
// Persistent encoder: grid (8,32); domain = blockIdx.x (32 jb-blocks, one XCD
// under round-robin placement). Probe-validated fence-free barrier; sc0 loads
// for the cross-block hin staging. Weights + c in registers.
// ---------------------------------------------------------------------------
__launch_bounds__(256, 1)
__global__ void enc_persist(f16* __restrict__ hA, f16* __restrict__ hB,
                            float* __restrict__ cbuf, const f16* __restrict__ Wfm,
                            const float* __restrict__ einp, f16* __restrict__ hx,
                            u32* __restrict__ barC, u32* __restrict__ barG,
                            u32* __restrict__ barCan){
  __shared__ f16 hsm[32*STR];
  __shared__ float gt[64][33];
  const int tid = threadIdx.x;
  const int bx = blockIdx.x, jb = blockIdx.y;
  const int id = bx + 8*jb;          // linear (x-fastest)
  const int b0 = bx*32;
  const int lane = tid & 63, w = tid>>6;
  const int rt = w & 1, ctb = (w>>1)*2;
  const int m = lane & 15, q = lane>>4;

  // weights -> registers (loop-invariant, statically indexed)
  f16x8 bf0[17], bf1[17];
  {
    const f16x8* bp0 = (const f16x8*)Wfm + ((size_t)(jb*4+ctb  )*17)*64 + lane;
    const f16x8* bp1 = (const f16x8*)Wfm + ((size_t)(jb*4+ctb+1)*17)*64 + lane;
    #pragma unroll
    for(int kk=0;kk<17;kk++){ bf0[kk] = bp0[kk*64]; bf1[kk] = bp1[kk*64]; }
  }
  float creg[2] = {0.f, 0.f};
  u32* ctr = barC + bx*64;           // 256B-spaced domain counters
  u32* flg = barG + bx*64;

  const int slow = probe32(ctr, barCan, flg, id, bx, tid);
  u32 gen = 4;

  const f16* hin = hA; f16* hout = hB;
  for(int t=0;t<SS;t++){
    {
      int row = tid>>3, c0 = tid&7;
      const u32* s32 = (const u32*)(hin + (size_t)(b0+row)*HH);
      u32* d32 = (u32*)(hsm + row*STR);
      #pragma unroll
      for(int i=0;i<8;i++){
        int ci = (c0 + 8*i)*4;
        *(uint4*)(d32 + ci) = ld4_sc0(s32 + ci);    // L1-bypass: cross-block data
      }
    }
    if(tid < 128){
      int row = tid>>2, pc = tid&3;
      union { f16 h[8]; uint4 u4; } z;
      #pragma unroll
      for(int j=0;j<8;j++) z.h[j] = (f16)0.0f;
      if(pc==0){ z.h[0] = (f16)einp[(size_t)(b0+row)*SS + t]; z.h[1] = (f16)1.0f; }
      *((uint4*)(hsm + row*STR) + 64 + pc) = z.u4;
    }
    __syncthreads();

    f32x4 acc0 = {0.f,0.f,0.f,0.f}, acc1 = {0.f,0.f,0.f,0.f};
    const f16* arow = hsm + (rt*16 + m)*STR + q*8;
    #pragma unroll
    for(int kk=0;kk<17;kk++){
      f16x8 a = *(const f16x8*)(arow + kk*32);
      acc0 = __builtin_amdgcn_mfma_f32_16x16x32_f16(a, bf0[kk], acc0, 0,0,0);
      acc1 = __builtin_amdgcn_mfma_f32_16x16x32_f16(a, bf1[kk], acc1, 0,0,0);
    }
    #pragma unroll
    for(int r=0;r<4;r++){
      gt[(ctb  )*16 + m][rt*16 + q*4 + r] = acc0[r];   // C/D: col=lane&15, row=4q+r
      gt[(ctb+1)*16 + m][rt*16 + q*4 + r] = acc1[r];
    }
    __syncthreads();

    #pragma unroll
    for(int qq=0;qq<2;qq++){
      int idx = tid + qq*256;
      int jc = idx & 15, rr = idx >> 4;
      float gi = gt[jc][rr];
      float gf = gt[16+jc][rr];
      float gg = gt[32+jc][rr];
      float go = gt[48+jc][rr];
      int b = b0 + rr, j = jb*16 + jc;
      float cv = sigm(gf)*creg[qq] + sigm(gi)*tanh_f(gg);
      creg[qq] = cv;
      float hv = sigm(go)*tanh_f(cv);
      hout[(size_t)b*HH + j] = (f16)hv;
      hx[((size_t)b*SS + t)*HH + j] = (f16)hv;
      if(t == SS-1) cbuf[(size_t)b*HH + j] = cv;   // handoff c_N to decoder
    }
    if(t != SS-1){ ++gen; bar32(ctr, 32u*gen, slow); }
    const f16* tmp = hin; hin = hout; hout = (f16*)tmp;
  }
}

// ---------------------------------------------------------------------------
// Persistent decoder: grid 256; domain g = id&7 (32 blocks, one XCD under
// round-robin). Roles remapped batch-local per domain:
//   phase1 qproj:  k<8  -> batches [32g,32g+32), jbq=k
//   phase2 attn:   b = 32g + k   (register-prefetch pipelined tiles)
//   phase3 LSTM:   chunk c = 2g + (k>=16), jbd = k&15
// sc0 loads for hin/qt/ctx (step-produced); probe-validated barriers.
// ---------------------------------------------------------------------------
__launch_bounds__(256, 1)
__global__ void dec_persist(f16* __restrict__ hA, f16* __restrict__ hB,
                            float* __restrict__ cbuf, f16* __restrict__ ctx,
                            const f16* __restrict__ Wdec, const f16* __restrict__ Wqf,
                            const f16* __restrict__ hx, float* __restrict__ qt,
                            f16* __restrict__ hdec, u32* __restrict__ barC,
                            u32* __restrict__ barG, u32* __restrict__ barCan){
  // phases never overlap in time (barriers between) -> union the big buffers
  __shared__ __align__(16) char smem[32*STR*2];   // 35,328 B >= xs(33,280) >= hsmd(34,048)
  __shared__ float gtd[128][17];                  // phase-3 scratch; qsm overlay in phase 2
  __shared__ float sc[32];

  const int tid = threadIdx.x;
  const int id  = blockIdx.x;
  const int g = id & 7, k = id >> 3;
  const int lane = tid & 63, w = tid>>6;

  u32* ctr = barC + g*64;
  u32* flg = barG + g*64;
  const int slow = probe32(ctr, barCan, flg, id, g, tid);
  u32 gen = 4;

  // decoder cell state -> registers (ownership = phase-3 role, fixed)
  const int b0d = g*32 + ((k & 16) ? 16 : 0);
  const int jbd = k & 15;
  float creg[2];
  #pragma unroll
  for(int qq=0;qq<2;qq++){
    int idx = tid + qq*256;
    int jc = idx & 31, rr = idx >> 5;
    creg[qq] = cbuf[(size_t)(b0d+rr)*HH + (jbd*32 + jc)];
  }

  for(int t=0;t<TT;t++){
    const f16* hin = (t&1) ? hB : hA;
    f16*       hout= (t&1) ? hA : hB;

    // ---------------- phase 1: qproj (k<8) ----------------
    if(k < 8){
      f16* hsmq = (f16*)smem;
      const int b0 = g*32, jbq = k;
      {
        int row = tid>>3, c0 = tid&7;
        const u32* s32 = (const u32*)(hin + (size_t)(b0+row)*HH);
        u32* d32 = (u32*)(hsmq + row*STR);
        #pragma unroll
        for(int i=0;i<8;i++){
          int ci = (c0 + 8*i)*4;
          *(uint4*)(d32 + ci) = ld4_sc0(s32 + ci);
        }
      }
      if(tid < 128){
        int row = tid>>2, pc = tid&3;
        union { f16 h[8]; uint4 u4; } z;
        #pragma unroll
        for(int j=0;j<8;j++) z.h[j] = (f16)0.0f;
        if(pc==0) z.h[0] = (f16)1.0f;
        *((uint4*)(hsmq + row*STR) + 64 + pc) = z.u4;
      }
      __syncthreads();
      const int rt = w & 1, ctb = (w>>1)*2;
      const int mm = lane & 15, q = lane>>4;
      f32x4 acc0 = {0.f,0.f,0.f,0.f}, acc1 = {0.f,0.f,0.f,0.f};
      const f16* arow = hsmq + (rt*16 + mm)*STR + q*8;
      const f16x8* bp0 = (const f16x8*)Wqf + ((size_t)(jbq*4+ctb  )*17)*64 + lane;
      const f16x8* bp1 = (const f16x8*)Wqf + ((size_t)(jbq*4+ctb+1)*17)*64 + lane;
      #pragma unroll
      for(int kk=0;kk<17;kk++){
        f16x8 a  = *(const f16x8*)(arow + kk*32);
        acc0 = __builtin_amdgcn_mfma_f32_16x16x32_f16(a, bp0[kk*64], acc0, 0,0,0);
        acc1 = __builtin_amdgcn_mfma_f32_16x16x32_f16(a, bp1[kk*64], acc1, 0,0,0);
      }
      #pragma unroll
      for(int r=0;r<4;r++){
        int b = b0 + rt*16 + q*4 + r;
        qt[(size_t)b*HH + jbq*64 + (ctb  )*16 + mm] = acc0[r];
        qt[(size_t)b*HH + jbq*64 + (ctb+1)*16 + mm] = acc1[r];
      }
    }
    ++gen; bar32(ctr, 32u*gen, slow);

    // ---------------- phase 2: attn (b = 32g + k), pipelined ----------------
    {
      unsigned short (*xs)[520] = (unsigned short(*)[520])smem;
      float* qsm = &gtd[0][0];               // [8][65] padded q staging (2,080 B)
      const int b = g*32 + k;
      const int seg = tid & 7, sp = tid >> 3;

      // stage q[b][:] via LDS once (512 sc0 dwords instead of 16K)
      {
        int i2 = tid*2;
        u32 q0 = ld_sc0((const u32*)qt + (size_t)b*HH + i2);
        u32 q1 = ld_sc0((const u32*)qt + (size_t)b*HH + i2 + 1);
        qsm[(i2>>6)*65 + (i2&63)]     = __uint_as_float(q0);
        qsm[((i2+1)>>6)*65 + ((i2+1)&63)] = __uint_as_float(q1);
      }
      __syncthreads();
      float qreg[64];
      #pragma unroll
      for(int i=0;i<64;i++) qreg[i] = qsm[seg*65 + i];

      float mx = -1e30f, l = 0.f, a0 = 0.f, a1 = 0.f;
      const uint4* src = (const uint4*)(hx + (size_t)b*SS*HH);

      // register prefetch pipeline: pf holds tile 'tile'; issue tile+1 early
      uint4 pf[8];
      #pragma unroll
      for(int kk=0;kk<8;kk++) pf[kk] = src[kk*256 + tid];

      for(int tile=0; tile<16; ++tile){
        __syncthreads();                       // xs free (prev PV done)
        #pragma unroll
        for(int kk=0;kk<8;kk++){
          int e  = (kk*256 + tid)*8;
          *(uint4*)&xs[e>>9][e&511] = pf[kk];  // waits vmcnt for pf
        }
        if(tile < 15){
          const uint4* tsrc = src + (size_t)(tile+1)*2048;
          #pragma unroll
          for(int kk=0;kk<8;kk++) pf[kk] = tsrc[kk*256 + tid];  // in flight during compute
        }
        __syncthreads();                       // xs ready

        float p = 0.f;
        const uint4* xrow = (const uint4*)&xs[sp][seg*64];
        #pragma unroll
        for(int i=0;i<8;i++){
          uint4 vv = xrow[i];
          float2 t0 = cvt2(vv.x), t1 = cvt2(vv.y), t2 = cvt2(vv.z), t3 = cvt2(vv.w);
          p = fmaf(qreg[i*8+0], t0.x, p);
          p = fmaf(qreg[i*8+1], t0.y, p);
          p = fmaf(qreg[i*8+2], t1.x, p);
          p = fmaf(qreg[i*8+3], t1.y, p);
          p = fmaf(qreg[i*8+4], t2.x, p);
          p = fmaf(qreg[i*8+5], t2.y, p);
          p = fmaf(qreg[i*8+6], t3.x, p);
          p = fmaf(qreg[i*8+7], t3.y, p);
        }
        p += __shfl_xor(p, 1);
        p += __shfl_xor(p, 2);
        p += __shfl_xor(p, 4);
        if(seg == 0) sc[sp] = p;
        __syncthreads();

        float tmax = -1e30f;
        #pragma unroll
        for(int s2=0;s2<32;s2++) tmax = fmaxf(tmax, sc[s2]);
        float mnew  = fmaxf(mx, tmax);
        float alpha = __expf(mx - mnew);
        a0 *= alpha; a1 *= alpha; l *= alpha;
        #pragma unroll 4
        for(int s2=0;s2<32;s2++){
          float pv = __expf(sc[s2] - mnew);
          l += pv;
          u32 xv = *(const u32*)&xs[s2][2*tid];
          float2 xf = cvt2(xv);
          a0 = fmaf(pv, xf.x, a0);
          a1 = fmaf(pv, xf.y, a1);
        }
        mx = mnew;
      }
      float inv = 1.0f/l;
      union { u32 u; f16 h[2]; } pk;
      pk.h[0] = (f16)(a0*inv); pk.h[1] = (f16)(a1*inv);
      *(u32*)(ctx + (size_t)b*HH + 2*tid) = pk.u;
    }
    ++gen; bar32(ctr, 32u*gen, slow);

    // ---------------- phase 3: decoder LSTM (chunk b0d, jbd) ----------------
    {
      f16* hsmd = (f16*)smem;
      {
        int row = tid>>4, c0 = tid&15;
        const u32* sh = (const u32*)(hin + (size_t)(b0d+row)*HH);
        const u32* sx = (const u32*)(ctx + (size_t)(b0d+row)*HH);
        u32* d32 = (u32*)(hsmd + row*STRD);
        #pragma unroll
        for(int i=0;i<8;i++){
          int c = c0 + 16*i;
          const u32* s = (c < 64) ? (sh + c*4) : (sx + (c-64)*4);
          *(uint4*)(d32 + c*4) = ld4_sc0(s);
        }
      }
      if(tid < 64){
        int row = tid>>2, pc = tid&3;
        union { f16 h[8]; uint4 u4; } z;
        #pragma unroll
        for(int j=0;j<8;j++) z.h[j] = (f16)0.0f;
        if(pc==0) z.h[0] = (f16)1.0f;
        *((uint4*)(hsmd + row*STRD) + 128 + pc) = z.u4;
      }
      __syncthreads();
      const int ctb = w*2;
      const int mm = lane & 15, q = lane>>4;
      f32x4 acc0 = {0.f,0.f,0.f,0.f}, acc1 = {0.f,0.f,0.f,0.f};
      const f16* arow = hsmd + mm*STRD + q*8;
      const f16x8* bp0 = (const f16x8*)Wdec + ((size_t)(jbd*8+ctb  )*33)*64 + lane;
      const f16x8* bp1 = (const f16x8*)Wdec + ((size_t)(jbd*8+ctb+1)*33)*64 + lane;
      #pragma unroll
      for(int kk=0;kk<33;kk++){
        f16x8 a  = *(const f16x8*)(arow + kk*32);
        acc0 = __builtin_amdgcn_mfma_f32_16x16x32_f16(a, bp0[kk*64], acc0, 0,0,0);
        acc1 = __builtin_amdgcn_mfma_f32_16x16x32_f16(a, bp1[kk*64], acc1, 0,0,0);
      }
      #pragma unroll
      for(int r=0;r<4;r++){
        gtd[(ctb  )*16 + mm][q*4 + r] = acc0[r];
        gtd[(ctb+1)*16 + mm][q*4 + r] = acc1[r];
      }
      __syncthreads();
      #pragma unroll
      for(int qq=0;qq<2;qq++){
        int idx = tid + qq*256;
        int jc = idx & 31, rr = idx >> 5;
        float gi = gtd[jc][rr];
        float gf = gtd[32+jc][rr];
        float gg = gtd[64+jc][rr];
        float go = gtd[96+jc][rr];
        int b = b0d + rr, j = jbd*32 + jc;
        float cv = sigm(gf)*creg[qq] + sigm(gi)*tanh_f(gg);
        creg[qq] = cv;
        float hv = sigm(go)*tanh_f(cv);
        hout[(size_t)b*HH + j] = (f16)hv;
        hdec[((size_t)t*BB + b)*HH + j] = (f16)hv;
      }
    }
    if(t != TT-1){ ++gen; bar32(ctr, 32u*gen, slow); }
  }
}

// out[b,t] = hdec[t,b,:] . out_W + out_b
__launch_bounds__(256)
__global__ void final_out(const f16* __restrict__ hdec, const float* __restrict__ outW,
                          const float* __restrict__ outb, float* __restrict__ out){
  __shared__ float w[HH];
  int t = blockIdx.x;
  for(int i=threadIdx.x;i<HH;i+=256) w[i] = outW[i];
  __syncthreads();
  int b = threadIdx.x;
  const uint4* hp = (const uint4*)(hdec + ((size_t)t*BB + b)*HH);
  float s = 0.f;
  #pragma unroll 4
  for(int j=0;j<HH/8;j++){
    uint4 hv = hp[j];
    float2 t0 = cvt2(hv.x), t1 = cvt2(hv.y), t2 = cvt2(hv.z), t3 = cvt2(hv.w);
    s = fmaf(t0.x, w[j*8+0], s); s = fmaf(t0.y, w[j*8+1], s);
    s = fmaf(t1.x, w[j*8+2], s); s = fmaf(t1.y, w[j*8+3], s);
    s = fmaf(t2.x, w[j*8+4], s); s = fmaf(t2.y, w[j*8+5], s);
    s = fmaf(t3.x, w[j*8+6], s); s = fmaf(t3.y, w[j*8+7], s);
  }
  out[(size_t)b*TT + t] = s + outb[0];
}

// ---------------------------------------------------------------------------
extern "C" void kernel_launch(void* const* d_in, const int* in_sizes, int n_in,
                              void* d_out, int out_size, void* d_ws, size_t ws_size,
                              hipStream_t stream){
  const float* enc_in = (const float*)d_in[0];
  const float* embW = (const float*)d_in[2];
  const float* embB = (const float*)d_in[3];
  const float* eWih = (const float*)d_in[4];
  const float* eWhh = (const float*)d_in[5];
  const float* ebih = (const float*)d_in[6];
  const float* ebhh = (const float*)d_in[7];
  const float* dWih = (const float*)d_in[8];
  const float* dWhh = (const float*)d_in[9];
  const float* dbih = (const float*)d_in[10];
  const float* dbhh = (const float*)d_in[11];
  const float* Wq   = (const float*)d_in[12];
  const float* bq   = (const float*)d_in[13];
  const float* Wk   = (const float*)d_in[14];
  // d_in[15]: bk — softmax-invariant, unused
  const float* outW = (const float*)d_in[16];
  const float* outb = (const float*)d_in[17];

  // ---- workspace layout (byte offsets, all 16B-aligned) ----
  char* base = (char*)d_ws;
  f16* Wenc = (f16*)(base + 0);              // 128*17*64*8 f16 = 2,228,224 B
  f16* Wdec = (f16*)(base + 2228224);        // 128*33*64*8 f16 = 4,325,376 B
  f16* Wqf  = (f16*)(base + 6553600);        // 32*17*64*8 f16 = 557,056 B
  f16* hb0  = (f16*)(base + 7110656);        // 262,144 B
  f16* hb1  = (f16*)(base + 7372800);        // 262,144 B
  f16* ctx  = (f16*)(base + 7634944);        // 262,144 B
  f16* hdec = (f16*)(base + 7897088);        // 25,165,824 B
  f16* hx   = (f16*)(base + 33062912);       // 134,217,728 B
  float* u     = (float*)(base + 167280640); // 8,192 B
  float* v     = (float*)(base + 167288832);
  float* bd    = (float*)(base + 167297024);
  float* bqk   = (float*)(base + 167305216); // 2,048 B
  float* Wqk_t = (float*)(base + 167307264); // 1,048,576 B (dead after prep_wqfm)
  float* cb    = (float*)(base + 168355840); // 524,288 B
  float* qt    = (float*)(base + 168880128); // 524,288 B
  // barrier area overlays dead Wqk_t (live only after prep_wqfm):
  const size_t WOFF = 167307264;
  u32* encCtr = (u32*)(base + WOFF);             // 8 × 256B
  u32* encFlg = (u32*)(base + WOFF + 2048);      // 8 × 256B
  u32* encCan = (u32*)(base + WOFF + 4096);      // 256 × 256B
  u32* decCtr = (u32*)(base + WOFF + 69632);     // 8 × 256B
  u32* decFlg = (u32*)(base + WOFF + 71680);     // 8 × 256B
  u32* decCan = (u32*)(base + WOFF + 73728);     // 256 × 256B (ends 139,264)

  hipMemsetAsync(hb0, 0, (size_t)BB*HH*sizeof(f16), stream);
  hipMemsetAsync(cb,  0, (size_t)BB*HH*sizeof(float), stream);

  prep_uv  <<<8, 256, 0, stream>>>(eWih, embW, embB, ebih, ebhh, dbih, dbhh, u, v, bd);
  prep_bqk <<<2, 256, 0, stream>>>(bq, Wk, bqk);
  prep_wqk <<<512, 256, 0, stream>>>(Wq, Wk, Wqk_t);
  prep_wenc<<<dim3(128,17), 64, 0, stream>>>(eWhh, u, v, Wenc);
  prep_wdec<<<dim3(128,33), 64, 0, stream>>>(dWih, dWhh, bd, Wdec);
  prep_wqfm<<<dim3(32,17),  64, 0, stream>>>(Wqk_t, bqk, Wqf);

  // zero barrier counters/canaries (after prep_wqfm consumed Wqk_t)
  hipMemsetAsync(encCtr, 0, 139264, stream);

  f16* hbuf[2] = {hb0, hb1};

  // ---- encoder: persistent (coop launch for residency guarantee), fallback ----
  {
    void* eargs[9] = { (void*)&hb0, (void*)&hb1, (void*)&cb, (void*)&Wenc,
                       (void*)&enc_in, (void*)&hx,
                       (void*)&encCtr, (void*)&encFlg, (void*)&encCan };
    hipError_t ce = hipLaunchCooperativeKernel((const void*)enc_persist,
                                               dim3(8,32), dim3(256), eargs, 0, stream);
    if(ce != hipSuccess){
      for(int t=0;t<SS;t++){
        enc_step<<<dim3(8,32), 256, 0, stream>>>(hbuf[t&1], hbuf[(t+1)&1], cb,
                                                 Wenc, enc_in, hx, t);
      }
    }
  }

  // ---- decoder: persistent (coop launch), fallback ----
  {
    void* dargs[12] = { (void*)&hb0, (void*)&hb1, (void*)&cb, (void*)&ctx,
                        (void*)&Wdec, (void*)&Wqf, (void*)&hx, (void*)&qt,
                        (void*)&hdec, (void*)&decCtr, (void*)&decFlg, (void*)&decCan };
    hipError_t cd = hipLaunchCooperativeKernel((const void*)dec_persist,
                                               dim3(256), dim3(256), dargs, 0, stream);
    if(cd != hipSuccess){
      for(int t=0;t<TT;t++){
        qproj   <<<dim3(8,8),  256, 0, stream>>>(hbuf[t&1], Wqf, qt);
        attn    <<<256, 256, 0, stream>>>(qt, hx, ctx);
        dec_step<<<dim3(16,16),256, 0, stream>>>(hbuf[t&1], hbuf[(t+1)&1], cb, ctx,
                                                 Wdec, hdec, t);
      }
    }
  }

  final_out<<<TT, 256, 0, stream>>>(hdec, outW, outb, (float*)d_out);
}

// Round 6
// 10230.082 us; speedup vs baseline: 1.2226x; 1.2226x over previous
//
#include <hip/hip_runtime.h>
#include <hip/hip_bf16.h>
#include <cstdint>
#include <cstddef>

#define BB   256   // batch
#define SS   512   // encoder seq len
#define RDIM 128   // embed dim
#define HH   512   // hidden
#define TT   96    // decoder steps

typedef unsigned int u32;
typedef _Float16 f16;
typedef __attribute__((ext_vector_type(8))) _Float16 f16x8;
typedef __attribute__((ext_vector_type(4))) float f32x4;

__device__ __forceinline__ float sigm(float x){ return 1.0f/(1.0f+__expf(-x)); }
__device__ __forceinline__ float tanh_f(float x){ return 1.0f - 2.0f/(__expf(2.0f*x)+1.0f); }
__device__ __forceinline__ float2 cvt2(u32 x){
  union { u32 u; f16 h[2]; } t; t.u = x;
  return make_float2((float)t.h[0], (float)t.h[1]);
}

__device__ __forceinline__ void fence_rel(){ __builtin_amdgcn_fence(__ATOMIC_RELEASE, "agent"); }
__device__ __forceinline__ void fence_acq(){ __builtin_amdgcn_fence(__ATOMIC_ACQUIRE, "agent"); }

// L1-bypassing dword load (agent-scope relaxed atomic -> sc0, reads L2/IC).
__device__ __forceinline__ u32 ld_sc0(const u32* p){
  return __hip_atomic_load((u32*)p, __ATOMIC_RELAXED, __HIP_MEMORY_SCOPE_AGENT);
}
__device__ __forceinline__ uint4 ld4_sc0(const u32* p){
  return make_uint4(ld_sc0(p), ld_sc0(p+1), ld_sc0(p+2), ld_sc0(p+3));
}

// async global -> LDS, 16B per lane; LDS dest = wave-uniform base + lane*16
__device__ __forceinline__ void gload16(const void* g, void* l){
  __builtin_amdgcn_global_load_lds(
      (const __attribute__((address_space(1))) void*)g,
      (__attribute__((address_space(3))) void*)l, 16, 0, 0);
}

#define SPIN_CAP 50000   // escape hatch; legit waits are << this

// 32-block flag barrier: each block stores gen to its own 128B-spaced slot;
// 32 threads poll the 32 slots in parallel (no RMW serialization).
// slow=1 adds R3-proven agent fences for cross-XCD correctness.
__device__ __forceinline__ void bar32f(u32* flags, int slot, u32 gen, int slow){
  __syncthreads();                 // all waves' stores drained (vmcnt 0)
  if(threadIdx.x == 0){
    if(slow) fence_rel();
    __hip_atomic_store(&flags[slot*32], gen, __ATOMIC_RELAXED, __HIP_MEMORY_SCOPE_AGENT);
  }
  if(threadIdx.x < 32){
    int spins = 0;
    while(__hip_atomic_load(&flags[threadIdx.x*32], __ATOMIC_RELAXED, __HIP_MEMORY_SCOPE_AGENT) < gen){
      __builtin_amdgcn_s_sleep(2);
      if(++spins > SPIN_CAP) break;
    }
  }
  __syncthreads();
  if(slow){
    if(threadIdx.x == 0) fence_acq();
    __syncthreads();
  }
}

// Fence-free-mode validity probe (2 rounds of canary store / fast barrier /
// sc0 peer read). Any stale read -> domain err flag -> slow barriers.
// Consumes generations 1..4; caller continues from gen=4.
__device__ __forceinline__ int probe32f(u32* flags, int slot, u32* can, u32* flg,
                                        int id, int g, int tid){
  __shared__ u32 okf;
  u32 gen = 0;
  #pragma unroll
  for(int r=0;r<2;r++){
    u32 tag = r ? 0x5A5A0000u : 0xA5A50000u;
    if(tid==0) can[(size_t)id*64 + r] = tag + (u32)id;   // plain store -> L2
    ++gen; bar32f(flags, slot, gen, 0);
    if(tid==0) okf = 1u;
    __syncthreads();
    if(tid < 32){
      int mid = g + 8*tid;                                // domain members
      u32 v = ld_sc0(can + (size_t)mid*64 + r);
      if(v != tag + (u32)mid) okf = 0u;                   // benign race (1->0)
    }
    __syncthreads();
    if(tid==0 && okf==0u)
      __hip_atomic_store(flg, 1u, __ATOMIC_RELAXED, __HIP_MEMORY_SCOPE_AGENT);
    ++gen; bar32f(flags, slot, gen, 0);
  }
  return (int)__hip_atomic_load(flg, __ATOMIC_RELAXED, __HIP_MEMORY_SCOPE_AGENT);
}

// ---------------------------------------------------------------------------
// Prep kernels (unchanged, r0-verified)
// ---------------------------------------------------------------------------

__global__ void prep_uv(const float* __restrict__ Wih, const float* __restrict__ embW,
                        const float* __restrict__ embB, const float* __restrict__ bih,
                        const float* __restrict__ bhh, const float* __restrict__ dbih,
                        const float* __restrict__ dbhh,
                        float* __restrict__ u, float* __restrict__ v, float* __restrict__ bd){
  int n = blockIdx.x*256 + threadIdx.x;   // 0..2047
  const float* row = Wih + (size_t)n*RDIM;
  float su = 0.f, sv = 0.f;
  for(int r=0;r<RDIM;r++){ float w = row[r]; su += w*embW[r]; sv += w*embB[r]; }
  u[n] = su;
  v[n] = sv + bih[n] + bhh[n];
  bd[n] = dbih[n] + dbhh[n];
}

__global__ void prep_wqk(const float* __restrict__ Wq, const float* __restrict__ Wk,
                         float* __restrict__ Wqk_t){
  __shared__ float wkc[HH];
  int n = blockIdx.x;
  for(int i=threadIdx.x;i<HH;i+=256) wkc[i] = Wk[(size_t)i*HH + n];
  __syncthreads();
  for(int a=threadIdx.x;a<HH;a+=256){
    float s = 0.f;
    for(int hp=0;hp<HH;hp++) s += Wq[(size_t)hp*HH + a]*wkc[hp];
    Wqk_t[(size_t)n*HH + a] = s;
  }
}

__global__ void prep_bqk(const float* __restrict__ bq, const float* __restrict__ Wk,
                         float* __restrict__ bqk){
  int n = blockIdx.x*256 + threadIdx.x;
  float s = 0.f;
  for(int hp=0;hp<HH;hp++) s += bq[hp]*Wk[(size_t)hp*HH + n];
  bqk[n] = s;
}

__global__ void prep_wenc(const float* __restrict__ Whh, const float* __restrict__ u,
                          const float* __restrict__ v, f16* __restrict__ Wfm){
  int nt = blockIdx.x, kk = blockIdx.y, L = threadIdx.x;
  int jb = nt>>2, ct = nt&3;
  int n = ct*HH + jb*16 + (L&15);
  int q = L>>4;
  union { f16 h[8]; uint4 u4; } z;
  if(kk < 16){
    const float* src = Whh + (size_t)n*HH + kk*32 + q*8;
    #pragma unroll
    for(int j=0;j<8;j++) z.h[j] = (f16)src[j];
  } else {
    #pragma unroll
    for(int j=0;j<8;j++) z.h[j] = (f16)0.0f;
    if(q==0){ z.h[0] = (f16)u[n]; z.h[1] = (f16)v[n]; }
  }
  *(uint4*)(Wfm + (((size_t)nt*17 + kk)*64 + L)*8) = z.u4;
}

__global__ void prep_wdec(const float* __restrict__ dWih, const float* __restrict__ dWhh,
                          const float* __restrict__ bd, f16* __restrict__ Wfm){
  int nt = blockIdx.x, kk = blockIdx.y, L = threadIdx.x;
  int jb = nt>>3, ct = nt&7;
  int n = (ct>>1)*HH + jb*32 + (ct&1)*16 + (L&15);
  int q = L>>4;
  union { f16 h[8]; uint4 u4; } z;
  if(kk < 32){
    int k0 = kk*32 + q*8;
    #pragma unroll
    for(int j=0;j<8;j++){
      float wv = dWih[(size_t)n*1024 + k0 + j];
      if(k0 + j < HH) wv += dWhh[(size_t)n*HH + k0 + j];
      z.h[j] = (f16)wv;
    }
  } else {
    #pragma unroll
    for(int j=0;j<8;j++) z.h[j] = (f16)0.0f;
    if(q==0) z.h[0] = (f16)bd[n];
  }
  *(uint4*)(Wfm + (((size_t)nt*33 + kk)*64 + L)*8) = z.u4;
}

__global__ void prep_wqfm(const float* __restrict__ Wqk_t, const float* __restrict__ bqk,
                          f16* __restrict__ Wfm){
  int nt = blockIdx.x, kk = blockIdx.y, L = threadIdx.x;
  int n = nt*16 + (L&15);
  int q = L>>4;
  union { f16 h[8]; uint4 u4; } z;
  if(kk < 16){
    const float* src = Wqk_t + (size_t)n*HH + kk*32 + q*8;
    #pragma unroll
    for(int j=0;j<8;j++) z.h[j] = (f16)src[j];
  } else {
    #pragma unroll
    for(int j=0;j<8;j++) z.h[j] = (f16)0.0f;
    if(q==0) z.h[0] = (f16)bqk[n];
  }
  *(uint4*)(Wfm + (((size_t)nt*17 + kk)*64 + L)*8) = z.u4;
}

// ---------------------------------------------------------------------------
// r0-VERIFIED standalone step kernels (fallback path)
// ---------------------------------------------------------------------------
#define STR 552   // LDS row stride in f16 (544 data + 8 pad)

__launch_bounds__(256)
__global__ void enc_step(const f16* __restrict__ hin, f16* __restrict__ hout,
                         float* __restrict__ cbuf, const f16* __restrict__ Wfm,
                         const float* __restrict__ einp, f16* __restrict__ hx, int t){
  __shared__ f16 hsm[32*STR];
  __shared__ float gt[64][33];
  const int tid = threadIdx.x;
  const int b0 = blockIdx.x*32, jb = blockIdx.y;

  {
    int row = tid>>3, c0 = tid&7;
    const uint4* src = (const uint4*)(hin + (size_t)(b0+row)*HH);
    uint4* drow = (uint4*)(hsm + row*STR);
    #pragma unroll
    for(int i=0;i<8;i++) drow[c0 + 8*i] = src[c0 + 8*i];
  }
  if(tid < 128){
    int row = tid>>2, pc = tid&3;
    union { f16 h[8]; uint4 u4; } z;
    #pragma unroll
    for(int j=0;j<8;j++) z.h[j] = (f16)0.0f;
    if(pc==0){ z.h[0] = (f16)einp[(size_t)(b0+row)*SS + t]; z.h[1] = (f16)1.0f; }
    *((uint4*)(hsm + row*STR) + 64 + pc) = z.u4;
  }
  __syncthreads();

  const int lane = tid & 63, w = tid>>6;
  const int rt = w & 1, ctb = (w>>1)*2;
  const int m = lane & 15, q = lane>>4;
  f32x4 acc0 = {0.f,0.f,0.f,0.f}, acc1 = {0.f,0.f,0.f,0.f};
  const f16* arow = hsm + (rt*16 + m)*STR + q*8;
  const f16x8* bp0 = (const f16x8*)Wfm + ((size_t)(jb*4+ctb  )*17)*64 + lane;
  const f16x8* bp1 = (const f16x8*)Wfm + ((size_t)(jb*4+ctb+1)*17)*64 + lane;
  #pragma unroll
  for(int kk=0;kk<17;kk++){
    f16x8 a  = *(const f16x8*)(arow + kk*32);
    f16x8 b0 = bp0[kk*64];
    f16x8 b1 = bp1[kk*64];
    acc0 = __builtin_amdgcn_mfma_f32_16x16x32_f16(a, b0, acc0, 0,0,0);
    acc1 = __builtin_amdgcn_mfma_f32_16x16x32_f16(a, b1, acc1, 0,0,0);
  }
  #pragma unroll
  for(int r=0;r<4;r++){
    gt[(ctb  )*16 + m][rt*16 + q*4 + r] = acc0[r];   // C/D: col=lane&15, row=4q+r
    gt[(ctb+1)*16 + m][rt*16 + q*4 + r] = acc1[r];
  }
  __syncthreads();

  #pragma unroll
  for(int qq=0;qq<2;qq++){
    int idx = tid + qq*256;
    int jc = idx & 15, rr = idx >> 4;
    float gi = gt[jc][rr];
    float gf = gt[16+jc][rr];
    float gg = gt[32+jc][rr];
    float go = gt[48+jc][rr];
    int b = b0 + rr, j = jb*16 + jc;
    size_t ci = (size_t)b*HH + j;
    float cv = sigm(gf)*cbuf[ci] + sigm(gi)*tanh_f(gg);
    cbuf[ci] = cv;
    float hv = sigm(go)*tanh_f(cv);
    hout[ci] = (f16)hv;
    hx[((size_t)b*SS + t)*HH + j] = (f16)hv;
  }
}

__launch_bounds__(256)
__global__ void qproj(const f16* __restrict__ hin, const f16* __restrict__ Wfm,
                      float* __restrict__ qt){
  __shared__ f16 hsm[32*STR];
  const int tid = threadIdx.x;
  const int b0 = blockIdx.x*32, jb = blockIdx.y;
  {
    int row = tid>>3, c0 = tid&7;
    const uint4* src = (const uint4*)(hin + (size_t)(b0+row)*HH);
    uint4* drow = (uint4*)(hsm + row*STR);
    #pragma unroll
    for(int i=0;i<8;i++) drow[c0 + 8*i] = src[c0 + 8*i];
  }
  if(tid < 128){
    int row = tid>>2, pc = tid&3;
    union { f16 h[8]; uint4 u4; } z;
    #pragma unroll
    for(int j=0;j<8;j++) z.h[j] = (f16)0.0f;
    if(pc==0) z.h[0] = (f16)1.0f;
    *((uint4*)(hsm + row*STR) + 64 + pc) = z.u4;
  }
  __syncthreads();

  const int lane = tid & 63, w = tid>>6;
  const int rt = w & 1, ctb = (w>>1)*2;
  const int m = lane & 15, q = lane>>4;
  f32x4 acc0 = {0.f,0.f,0.f,0.f}, acc1 = {0.f,0.f,0.f,0.f};
  const f16* arow = hsm + (rt*16 + m)*STR + q*8;
  const f16x8* bp0 = (const f16x8*)Wfm + ((size_t)(jb*4+ctb  )*17)*64 + lane;
  const f16x8* bp1 = (const f16x8*)Wfm + ((size_t)(jb*4+ctb+1)*17)*64 + lane;
  #pragma unroll
  for(int kk=0;kk<17;kk++){
    f16x8 a  = *(const f16x8*)(arow + kk*32);
    f16x8 b0 = bp0[kk*64];
    f16x8 b1 = bp1[kk*64];
    acc0 = __builtin_amdgcn_mfma_f32_16x16x32_f16(a, b0, acc0, 0,0,0);
    acc1 = __builtin_amdgcn_mfma_f32_16x16x32_f16(a, b1, acc1, 0,0,0);
  }
  #pragma unroll
  for(int r=0;r<4;r++){
    int b = b0 + rt*16 + q*4 + r;
    qt[(size_t)b*HH + jb*64 + (ctb  )*16 + m] = acc0[r];
    qt[(size_t)b*HH + jb*64 + (ctb+1)*16 + m] = acc1[r];
  }
}

__launch_bounds__(256)
__global__ void attn(const float* __restrict__ qt, const f16* __restrict__ hx,
                     f16* __restrict__ ctx){
  __shared__ unsigned short xs[32][520];
  __shared__ float sc[32];
  const int b = blockIdx.x, tid = threadIdx.x;
  const int seg = tid & 7;
  const int sp  = tid >> 3;

  float qreg[64];
  {
    const float4* qv = (const float4*)(qt + (size_t)b*HH + seg*64);
    #pragma unroll
    for(int i=0;i<16;i++){
      float4 v4 = qv[i];
      qreg[i*4+0]=v4.x; qreg[i*4+1]=v4.y; qreg[i*4+2]=v4.z; qreg[i*4+3]=v4.w;
    }
  }

  float m = -1e30f, l = 0.f, a0 = 0.f, a1 = 0.f;
  const uint4* src = (const uint4*)(hx + (size_t)b*SS*HH);

  for(int tile=0; tile<16; ++tile){
    __syncthreads();
    const uint4* tsrc = src + (size_t)tile*2048;
    #pragma unroll
    for(int kk=0;kk<8;kk++){
      uint4 vv = tsrc[kk*256 + tid];
      int e  = (kk*256 + tid)*8;
      int ss = e >> 9, hh = e & 511;
      *(uint4*)&xs[ss][hh] = vv;
    }
    __syncthreads();

    float p = 0.f;
    const uint4* xrow = (const uint4*)&xs[sp][seg*64];
    #pragma unroll
    for(int i=0;i<8;i++){
      uint4 vv = xrow[i];
      float2 t0 = cvt2(vv.x), t1 = cvt2(vv.y), t2 = cvt2(vv.z), t3 = cvt2(vv.w);
      p = fmaf(qreg[i*8+0], t0.x, p);
      p = fmaf(qreg[i*8+1], t0.y, p);
      p = fmaf(qreg[i*8+2], t1.x, p);
      p = fmaf(qreg[i*8+3], t1.y, p);
      p = fmaf(qreg[i*8+4], t2.x, p);
      p = fmaf(qreg[i*8+5], t2.y, p);
      p = fmaf(qreg[i*8+6], t3.x, p);
      p = fmaf(qreg[i*8+7], t3.y, p);
    }
    p += __shfl_xor(p, 1);
    p += __shfl_xor(p, 2);
    p += __shfl_xor(p, 4);
    if(seg == 0) sc[sp] = p;
    __syncthreads();

    float tmax = -1e30f;
    #pragma unroll
    for(int s2=0;s2<32;s2++) tmax = fmaxf(tmax, sc[s2]);
    float mnew  = fmaxf(m, tmax);
    float alpha = __expf(m - mnew);
    a0 *= alpha; a1 *= alpha; l *= alpha;
    #pragma unroll 4
    for(int s2=0;s2<32;s2++){
      float pv = __expf(sc[s2] - mnew);
      l += pv;
      u32 xv = *(const u32*)&xs[s2][2*tid];
      float2 xf = cvt2(xv);
      a0 = fmaf(pv, xf.x, a0);
      a1 = fmaf(pv, xf.y, a1);
    }
    m = mnew;
  }
  float inv = 1.0f/l;
  union { u32 u; f16 h[2]; } pk;
  pk.h[0] = (f16)(a0*inv); pk.h[1] = (f16)(a1*inv);
  *(u32*)(ctx + (size_t)b*HH + 2*tid) = pk.u;
}

#define STRD 1064  // 1056 data + 8 pad (2128B)

__launch_bounds__(256)
__global__ void dec_step(const f16* __restrict__ hin, f16* __restrict__ hout,
                         float* __restrict__ cbuf, const f16* __restrict__ ctxv,
                         const f16* __restrict__ Wfm, f16* __restrict__ hdec, int t){
  __shared__ f16 hsm[16*STRD];
  __shared__ float gt[128][17];
  const int tid = threadIdx.x;
  const int b0 = blockIdx.x*16, jb = blockIdx.y;

  {
    int row = tid>>4, c0 = tid&15;
    const uint4* srch = (const uint4*)(hin  + (size_t)(b0+row)*HH);
    const uint4* srcc = (const uint4*)(ctxv + (size_t)(b0+row)*HH);
    uint4* drow = (uint4*)(hsm + row*STRD);
    #pragma unroll
    for(int i=0;i<8;i++){
      int c = c0 + 16*i;
      drow[c] = (c < 64) ? srch[c] : srcc[c-64];
    }
  }
  if(tid < 64){
    int row = tid>>2, pc = tid&3;
    union { f16 h[8]; uint4 u4; } z;
    #pragma unroll
    for(int j=0;j<8;j++) z.h[j] = (f16)0.0f;
    if(pc==0) z.h[0] = (f16)1.0f;
    *((uint4*)(hsm + row*STRD) + 128 + pc) = z.u4;
  }
  __syncthreads();

  const int lane = tid & 63, w = tid>>6;
  const int ctb = w*2;
  const int m = lane & 15, q = lane>>4;
  f32x4 acc0 = {0.f,0.f,0.f,0.f}, acc1 = {0.f,0.f,0.f,0.f};
  const f16* arow = hsm + m*STRD + q*8;
  const f16x8* bp0 = (const f16x8*)Wfm + ((size_t)(jb*8+ctb  )*33)*64 + lane;
  const f16x8* bp1 = (const f16x8*)Wfm + ((size_t)(jb*8+ctb+1)*33)*64 + lane;
  #pragma unroll
  for(int kk=0;kk<33;kk++){
    f16x8 a  = *(const f16x8*)(arow + kk*32);
    f16x8 b0 = bp0[kk*64];
    f16x8 b1 = bp1[kk*64];
    acc0 = __builtin_amdgcn_mfma_f32_16x16x32_f16(a, b0, acc0, 0,0,0);
    acc1 = __builtin_amdgcn_mfma_f32_16x16x32_f16(a, b1, acc1, 0,0,0);
  }
  #pragma unroll
  for(int r=0;r<4;r++){
    gt[(ctb  )*16 + m][q*4 + r] = acc0[r];
    gt[(ctb+1)*16 + m][q*4 + r] = acc1[r];
  }
  __syncthreads();

  #pragma unroll
  for(int qq=0;qq<2;qq++){
    int idx = tid + qq*256;
    int jc = idx & 31, rr = idx >> 5;    // jc 0..31, rr 0..15
    float gi = gt[jc][rr];
    float gf = gt[32+jc][rr];
    float gg = gt[64+jc][rr];
    float go = gt[96+jc][rr];
    int b = b0 + rr, j = jb*32 + jc;
    size_t ci = (size_t)b*HH + j;
    float cv = sigm(gf)*cbuf[ci] + sigm(gi)*tanh_f(gg);
    cbuf[ci] = cv;
    float hv = sigm(go)*tanh_f(cv);
    hout[ci] = (f16)hv;
    hdec[((size_t)t*BB + b)*HH + j] = (f16)hv;
  }
}

// ---------------------------------------------------------------------------
// Persistent encoder: grid (8,32); domain = blockIdx.x. Flag barrier.
// ---------------------------------------------------------------------------
__launch_bounds__(256, 1)
__global__ void enc_persist(f16* __restrict__ hA, f16* __restrict__ hB,
                            float* __restrict__ cbuf, const f16* __restrict__ Wfm,
                            const float* __restrict__ einp, f16* __restrict__ hx,
                            u32* __restrict__ flg8, u32* __restrict__ err8,
                            u32* __restrict__ can){
  __shared__ f16 hsm[32*STR];
  __shared__ float gt[64][33];
  const int tid = threadIdx.x;
  const int bx = blockIdx.x, jb = blockIdx.y;
  const int id = bx + 8*jb;          // linear (x-fastest)
  const int b0 = bx*32;
  const int lane = tid & 63, w = tid>>6;
  const int rt = w & 1, ctb = (w>>1)*2;
  const int m = lane & 15, q = lane>>4;

  // weights -> registers (loop-invariant, statically indexed)
  f16x8 bf0[17], bf1[17];
  {
    const f16x8* bp0 = (const f16x8*)Wfm + ((size_t)(jb*4+ctb  )*17)*64 + lane;
    const f16x8* bp1 = (const f16x8*)Wfm + ((size_t)(jb*4+ctb+1)*17)*64 + lane;
    #pragma unroll
    for(int kk=0;kk<17;kk++){ bf0[kk] = bp0[kk*64]; bf1[kk] = bp1[kk*64]; }
  }
  float creg[2] = {0.f, 0.f};
  u32* flags = flg8 + bx*1024;       // 32 slots x 128B per domain
  u32* err   = err8 + bx*64;

  const int slow = probe32f(flags, jb, can, err, id, bx, tid);
  u32 gen = 4;

  const f16* hin = hA; f16* hout = hB;
  for(int t=0;t<SS;t++){
    {
      int row = tid>>3, c0 = tid&7;
      const u32* s32 = (const u32*)(hin + (size_t)(b0+row)*HH);
      u32* d32 = (u32*)(hsm + row*STR);
      #pragma unroll
      for(int i=0;i<8;i++){
        int ci = (c0 + 8*i)*4;
        *(uint4*)(d32 + ci) = ld4_sc0(s32 + ci);    // L1-bypass: cross-block data
      }
    }
    if(tid < 128){
      int row = tid>>2, pc = tid&3;
      union { f16 h[8]; uint4 u4; } z;
      #pragma unroll
      for(int j=0;j<8;j++) z.h[j] = (f16)0.0f;
      if(pc==0){ z.h[0] = (f16)einp[(size_t)(b0+row)*SS + t]; z.h[1] = (f16)1.0f; }
      *((uint4*)(hsm + row*STR) + 64 + pc) = z.u4;
    }
    __syncthreads();

    f32x4 acc0 = {0.f,0.f,0.f,0.f}, acc1 = {0.f,0.f,0.f,0.f};
    const f16* arow = hsm + (rt*16 + m)*STR + q*8;
    #pragma unroll
    for(int kk=0;kk<17;kk++){
      f16x8 a = *(const f16x8*)(arow + kk*32);
      acc0 = __builtin_amdgcn_mfma_f32_16x16x32_f16(a, bf0[kk], acc0, 0,0,0);
      acc1 = __builtin_amdgcn_mfma_f32_16x16x32_f16(a, bf1[kk], acc1, 0,0,0);
    }
    #pragma unroll
    for(int r=0;r<4;r++){
      gt[(ctb  )*16 + m][rt*16 + q*4 + r] = acc0[r];   // C/D: col=lane&15, row=4q+r
      gt[(ctb+1)*16 + m][rt*16 + q*4 + r] = acc1[r];
    }
    __syncthreads();

    #pragma unroll
    for(int qq=0;qq<2;qq++){
      int idx = tid + qq*256;
      int jc = idx & 15, rr = idx >> 4;
      float gi = gt[jc][rr];
      float gf = gt[16+jc][rr];
      float gg = gt[32+jc][rr];
      float go = gt[48+jc][rr];
      int b = b0 + rr, j = jb*16 + jc;
      float cv = sigm(gf)*creg[qq] + sigm(gi)*tanh_f(gg);
      creg[qq] = cv;
      float hv = sigm(go)*tanh_f(cv);
      hout[(size_t)b*HH + j] = (f16)hv;
      hx[((size_t)b*SS + t)*HH + j] = (f16)hv;
      if(t == SS-1) cbuf[(size_t)b*HH + j] = cv;   // handoff c_N to decoder
    }
    if(t != SS-1){ ++gen; bar32f(flags, jb, gen, slow); }
    const f16* tmp = hin; hin = hout; hout = (f16*)tmp;
  }
}

// ---------------------------------------------------------------------------
// Persistent decoder: grid 256; domain g = id&7. Flag barriers.
// attn: 3-buffer global_load_lds pipeline (2-tile lookahead, counted vmcnt),
// tiles 0,1 issued at step start (fly under qproj). q via LDS (no qreg).
// LDS: xs[3] = 99,840 B; hsmq/hsmd overlay xs[2] region (dead by then).
// ---------------------------------------------------------------------------
#define XTB 33280            // one attn tile buffer: 32 rows x 520 shorts
#define SMEMB (2*XTB + 35328) // 101,888: xs[0..2]; hsmq(35,328) at +2*XTB

__launch_bounds__(256, 1)
__global__ void dec_persist(f16* __restrict__ hA, f16* __restrict__ hB,
                            float* __restrict__ cbuf, f16* __restrict__ ctx,
                            const f16* __restrict__ Wdec, const f16* __restrict__ Wqf,
                            const f16* __restrict__ hx, float* __restrict__ qt,
                            f16* __restrict__ hdec, u32* __restrict__ flg8,
                            u32* __restrict__ err8, u32* __restrict__ can){
  __shared__ __align__(16) char smem[SMEMB];
  __shared__ __align__(16) float gtd[128][17];   // phase-3 gates; qsm overlay in phase 2
  __shared__ float sc[32];

  const int tid = threadIdx.x;
  const int id  = blockIdx.x;
  const int g = id & 7, k = id >> 3;
  const int lane = tid & 63, w = tid>>6;

  u32* flags = flg8 + g*1024;
  u32* err   = err8 + g*64;
  const int slow = probe32f(flags, k, can, err, id, g, tid);
  u32 gen = 4;

  // decoder cell state -> registers (ownership = phase-3 role, fixed)
  const int b0d = g*32 + ((k & 16) ? 16 : 0);
  const int jbd = k & 15;
  float creg[2];
  #pragma unroll
  for(int qq=0;qq<2;qq++){
    int idx = tid + qq*256;
    int jc = idx & 31, rr = idx >> 5;
    creg[qq] = cbuf[(size_t)(b0d+rr)*HH + (jbd*32 + jc)];
  }

  const int batt = g*32 + k;                       // attn batch for this block
  const char* hxb = (const char*)(hx + (size_t)batt*SS*HH);

  for(int t=0;t<TT;t++){
    const f16* hin = (t&1) ? hB : hA;
    f16*       hout= (t&1) ? hA : hB;

    // -------- issue attn tiles 0,1 (xs[0], xs[1]) — fly under qproj --------
    {
      #pragma unroll
      for(int pt=0; pt<2; ++pt){
        char* dst = smem + (size_t)pt*XTB;
        const char* srcb = hxb + (size_t)pt*32768 + (size_t)(w*8)*1024 + (size_t)lane*16;
        #pragma unroll
        for(int r=0;r<8;r++)
          gload16(srcb + (size_t)r*1024, dst + (size_t)(w*8+r)*1040);
      }
    }

    // ---------------- phase 1: qproj (k<8) ----------------
    if(k < 8){
      f16* hsmq = (f16*)(smem + 2*XTB);
      const int b0 = g*32, jbq = k;
      {
        int row = tid>>3, c0 = tid&7;
        const u32* s32 = (const u32*)(hin + (size_t)(b0+row)*HH);
        u32* d32 = (u32*)(hsmq + row*STR);
        #pragma unroll
        for(int i=0;i<8;i++){
          int ci = (c0 + 8*i)*4;
          *(uint4*)(d32 + ci) = ld4_sc0(s32 + ci);
        }
      }
      if(tid < 128){
        int row = tid>>2, pc = tid&3;
        union { f16 h[8]; uint4 u4; } z;
        #pragma unroll
        for(int j=0;j<8;j++) z.h[j] = (f16)0.0f;
        if(pc==0) z.h[0] = (f16)1.0f;
        *((uint4*)(hsmq + row*STR) + 64 + pc) = z.u4;
      }
      __syncthreads();
      const int rt = w & 1, ctb = (w>>1)*2;
      const int mm = lane & 15, q = lane>>4;
      f32x4 acc0 = {0.f,0.f,0.f,0.f}, acc1 = {0.f,0.f,0.f,0.f};
      const f16* arow = hsmq + (rt*16 + mm)*STR + q*8;
      const f16x8* bp0 = (const f16x8*)Wqf + ((size_t)(jbq*4+ctb  )*17)*64 + lane;
      const f16x8* bp1 = (const f16x8*)Wqf + ((size_t)(jbq*4+ctb+1)*17)*64 + lane;
      #pragma unroll
      for(int kk=0;kk<17;kk++){
        f16x8 a  = *(const f16x8*)(arow + kk*32);
        acc0 = __builtin_amdgcn_mfma_f32_16x16x32_f16(a, bp0[kk*64], acc0, 0,0,0);
        acc1 = __builtin_amdgcn_mfma_f32_16x16x32_f16(a, bp1[kk*64], acc1, 0,0,0);
      }
      #pragma unroll
      for(int r=0;r<4;r++){
        int b = b0 + rt*16 + q*4 + r;
        qt[(size_t)b*HH + jbq*64 + (ctb  )*16 + mm] = acc0[r];
        qt[(size_t)b*HH + jbq*64 + (ctb+1)*16 + mm] = acc1[r];
      }
    }
    ++gen; bar32f(flags, k, gen, slow);

    // ---------------- phase 2: attn (b = batt), async-pipelined ----------------
    {
      const int seg = tid & 7, sp = tid >> 3;
      float* qsm = &gtd[0][0];               // [8][68] padded floats

      // stage q to LDS (sc0 dwords); syncthreads also drains tiles 0,1 loads
      {
        int i2 = tid*2;
        u32 q0 = ld_sc0((const u32*)qt + (size_t)batt*HH + i2);
        u32 q1 = ld_sc0((const u32*)qt + (size_t)batt*HH + i2 + 1);
        qsm[((i2  )>>6)*68 + ((i2  )&63)] = __uint_as_float(q0);
        qsm[((i2+1)>>6)*68 + ((i2+1)&63)] = __uint_as_float(q1);
      }
      __syncthreads();                       // qsm visible; vmcnt drained to 0

      float mx = -1e30f, l = 0.f, a0 = 0.f, a1 = 0.f;

      for(int tile=0; tile<16; ++tile){
        unsigned short (*xb)[520] =
            (unsigned short(*)[520])(smem + (size_t)(tile%3)*XTB);
        // wait this tile's loads done (<=8 newest outstanding = tile+1's)
        if(tile < 15) asm volatile("s_waitcnt vmcnt(8)" ::: "memory");
        else          asm volatile("s_waitcnt vmcnt(0)" ::: "memory");
        __builtin_amdgcn_sched_barrier(0);
        __builtin_amdgcn_s_barrier();        // raw: does NOT drain vmcnt
        __builtin_amdgcn_sched_barrier(0);
        // issue tile+2 into buf (tile+2)%3 (freed: all waves past PV(tile-1))
        if(tile < 14){
          char* dst = smem + (size_t)((tile+2)%3)*XTB;
          const char* srcb = hxb + (size_t)(tile+2)*32768
                           + (size_t)(w*8)*1024 + (size_t)lane*16;
          #pragma unroll
          for(int r=0;r<8;r++)
            gload16(srcb + (size_t)r*1024, dst + (size_t)(w*8+r)*1040);
        }

        float p = 0.f;
        const uint4*  xrow = (const uint4*)&xb[sp][seg*64];
        const float4* qv   = (const float4*)&qsm[seg*68];
        #pragma unroll
        for(int i=0;i<8;i++){
          uint4 vv = xrow[i];
          float4 qa = qv[2*i], qb = qv[2*i+1];
          float2 t0 = cvt2(vv.x), t1 = cvt2(vv.y), t2 = cvt2(vv.z), t3 = cvt2(vv.w);
          p = fmaf(qa.x, t0.x, p);
          p = fmaf(qa.y, t0.y, p);
          p = fmaf(qa.z, t1.x, p);
          p = fmaf(qa.w, t1.y, p);
          p = fmaf(qb.x, t2.x, p);
          p = fmaf(qb.y, t2.y, p);
          p = fmaf(qb.z, t3.x, p);
          p = fmaf(qb.w, t3.y, p);
        }
        p += __shfl_xor(p, 1);
        p += __shfl_xor(p, 2);
        p += __shfl_xor(p, 4);
        if(seg == 0) sc[sp] = p;
        asm volatile("s_waitcnt lgkmcnt(0)" ::: "memory");
        __builtin_amdgcn_sched_barrier(0);
        __builtin_amdgcn_s_barrier();        // sc visible; vmcnt untouched
        __builtin_amdgcn_sched_barrier(0);

        float tmax = -1e30f;
        #pragma unroll
        for(int s2=0;s2<32;s2++) tmax = fmaxf(tmax, sc[s2]);
        float mnew  = fmaxf(mx, tmax);
        float alpha = __expf(mx - mnew);
        a0 *= alpha; a1 *= alpha; l *= alpha;
        #pragma unroll 4
        for(int s2=0;s2<32;s2++){
          float pv = __expf(sc[s2] - mnew);
          l += pv;
          u32 xv = *(const u32*)&xb[s2][2*tid];
          float2 xf = cvt2(xv);
          a0 = fmaf(pv, xf.x, a0);
          a1 = fmaf(pv, xf.y, a1);
        }
        mx = mnew;
      }
      float inv = 1.0f/l;
      union { u32 u; f16 h[2]; } pk;
      pk.h[0] = (f16)(a0*inv); pk.h[1] = (f16)(a1*inv);
      *(u32*)(ctx + (size_t)batt*HH + 2*tid) = pk.u;
    }
    ++gen; bar32f(flags, k, gen, slow);

    // ---------------- phase 3: decoder LSTM (chunk b0d, jbd) ----------------
    {
      f16* hsmd = (f16*)(smem + 2*XTB);
      {
        int row = tid>>4, c0 = tid&15;
        const u32* sh = (const u32*)(hin + (size_t)(b0d+row)*HH);
        const u32* sx = (const u32*)(ctx + (size_t)(b0d+row)*HH);
        u32* d32 = (u32*)(hsmd + row*STRD);
        #pragma unroll
        for(int i=0;i<8;i++){
          int c = c0 + 16*i;
          const u32* s = (c < 64) ? (sh + c*4) : (sx + (c-64)*4);
          *(uint4*)(d32 + c*4) = ld4_sc0(s);
        }
      }
      if(tid < 64){
        int row = tid>>2, pc = tid&3;
        union { f16 h[8]; uint4 u4; } z;
        #pragma unroll
        for(int j=0;j<8;j++) z.h[j] = (f16)0.0f;
        if(pc==0) z.h[0] = (f16)1.0f;
        *((uint4*)(hsmd + row*STRD) + 128 + pc) = z.u4;
      }
      __syncthreads();
      const int ctb = w*2;
      const int mm = lane & 15, q = lane>>4;
      f32x4 acc0 = {0.f,0.f,0.f,0.f}, acc1 = {0.f,0.f,0.f,0.f};
      const f16* arow = hsmd + mm*STRD + q*8;
      const f16x8* bp0 = (const f16x8*)Wdec + ((size_t)(jbd*8+ctb  )*33)*64 + lane;
      const f16x8* bp1 = (const f16x8*)Wdec + ((size_t)(jbd*8+ctb+1)*33)*64 + lane;
      #pragma unroll
      for(int kk=0;kk<33;kk++){
        f16x8 a  = *(const f16x8*)(arow + kk*32);
        acc0 = __builtin_amdgcn_mfma_f32_16x16x32_f16(a, bp0[kk*64], acc0, 0,0,0);
        acc1 = __builtin_amdgcn_mfma_f32_16x16x32_f16(a, bp1[kk*64], acc1, 0,0,0);
      }
      #pragma unroll
      for(int r=0;r<4;r++){
        gtd[(ctb  )*16 + mm][q*4 + r] = acc0[r];
        gtd[(ctb+1)*16 + mm][q*4 + r] = acc1[r];
      }
      __syncthreads();
      #pragma unroll
      for(int qq=0;qq<2;qq++){
        int idx = tid + qq*256;
        int jc = idx & 31, rr = idx >> 5;
        float gi = gtd[jc][rr];
        float gf = gtd[32+jc][rr];
        float gg = gtd[64+jc][rr];
        float go = gtd[96+jc][rr];
        int b = b0d + rr, j = jbd*32 + jc;
        float cv = sigm(gf)*creg[qq] + sigm(gi)*tanh_f(gg);
        creg[qq] = cv;
        float hv = sigm(go)*tanh_f(cv);
        hout[(size_t)b*HH + j] = (f16)hv;
        hdec[((size_t)t*BB + b)*HH + j] = (f16)hv;
      }
    }
    if(t != TT-1){ ++gen; bar32f(flags, k, gen, slow); }
  }
}

// out[b,t] = hdec[t,b,:] . out_W + out_b
__launch_bounds__(256)
__global__ void final_out(const f16* __restrict__ hdec, const float* __restrict__ outW,
                          const float* __restrict__ outb, float* __restrict__ out){
  __shared__ float w[HH];
  int t = blockIdx.x;
  for(int i=threadIdx.x;i<HH;i+=256) w[i] = outW[i];
  __syncthreads();
  int b = threadIdx.x;
  const uint4* hp = (const uint4*)(hdec + ((size_t)t*BB + b)*HH);
  float s = 0.f;
  #pragma unroll 4
  for(int j=0;j<HH/8;j++){
    uint4 hv = hp[j];
    float2 t0 = cvt2(hv.x), t1 = cvt2(hv.y), t2 = cvt2(hv.z), t3 = cvt2(hv.w);
    s = fmaf(t0.x, w[j*8+0], s); s = fmaf(t0.y, w[j*8+1], s);
    s = fmaf(t1.x, w[j*8+2], s); s = fmaf(t1.y, w[j*8+3], s);
    s = fmaf(t2.x, w[j*8+4], s); s = fmaf(t2.y, w[j*8+5], s);
    s = fmaf(t3.x, w[j*8+6], s); s = fmaf(t3.y, w[j*8+7], s);
  }
  out[(size_t)b*TT + t] = s + outb[0];
}

// ---------------------------------------------------------------------------
extern "C" void kernel_launch(void* const* d_in, const int* in_sizes, int n_in,
                              void* d_out, int out_size, void* d_ws, size_t ws_size,
                              hipStream_t stream){
  const float* enc_in = (const float*)d_in[0];
  const float* embW = (const float*)d_in[2];
  const float* embB = (const float*)d_in[3];
  const float* eWih = (const float*)d_in[4];
  const float* eWhh = (const float*)d_in[5];
  const float* ebih = (const float*)d_in[6];
  const float* ebhh = (const float*)d_in[7];
  const float* dWih = (const float*)d_in[8];
  const float* dWhh = (const float*)d_in[9];
  const float* dbih = (const float*)d_in[10];
  const float* dbhh = (const float*)d_in[11];
  const float* Wq   = (const float*)d_in[12];
  const float* bq   = (const float*)d_in[13];
  const float* Wk   = (const float*)d_in[14];
  // d_in[15]: bk — softmax-invariant, unused
  const float* outW = (const float*)d_in[16];
  const float* outb = (const float*)d_in[17];

  // ---- workspace layout (byte offsets, all 16B-aligned) ----
  char* base = (char*)d_ws;
  f16* Wenc = (f16*)(base + 0);              // 2,228,224 B
  f16* Wdec = (f16*)(base + 2228224);        // 4,325,376 B
  f16* Wqf  = (f16*)(base + 6553600);        // 557,056 B
  f16* hb0  = (f16*)(base + 7110656);        // 262,144 B
  f16* hb1  = (f16*)(base + 7372800);        // 262,144 B
  f16* ctx  = (f16*)(base + 7634944);        // 262,144 B
  f16* hdec = (f16*)(base + 7897088);        // 25,165,824 B
  f16* hx   = (f16*)(base + 33062912);       // 134,217,728 B
  float* u     = (float*)(base + 167280640); // 8,192 B
  float* v     = (float*)(base + 167288832);
  float* bd    = (float*)(base + 167297024);
  float* bqk   = (float*)(base + 167305216); // 2,048 B
  float* Wqk_t = (float*)(base + 167307264); // 1,048,576 B (dead after prep_wqfm)
  float* cb    = (float*)(base + 168355840); // 524,288 B
  float* qt    = (float*)(base + 168880128); // 524,288 B
  // barrier area overlays dead Wqk_t (live only after prep_wqfm):
  const size_t WOFF = 167307264;
  u32* encFlg = (u32*)(base + WOFF);             // 8 dom x 32 slots x 128B = 32,768
  u32* encErr = (u32*)(base + WOFF + 32768);     // 8 x 256B = 2,048
  u32* encCan = (u32*)(base + WOFF + 34816);     // 256 x 256B = 65,536
  u32* decFlg = (u32*)(base + WOFF + 100352);    // 32,768
  u32* decErr = (u32*)(base + WOFF + 133120);    // 2,048
  u32* decCan = (u32*)(base + WOFF + 135168);    // 65,536 (ends 200,704)

  hipMemsetAsync(hb0, 0, (size_t)BB*HH*sizeof(f16), stream);
  hipMemsetAsync(cb,  0, (size_t)BB*HH*sizeof(float), stream);

  prep_uv  <<<8, 256, 0, stream>>>(eWih, embW, embB, ebih, ebhh, dbih, dbhh, u, v, bd);
  prep_bqk <<<2, 256, 0, stream>>>(bq, Wk, bqk);
  prep_wqk <<<512, 256, 0, stream>>>(Wq, Wk, Wqk_t);
  prep_wenc<<<dim3(128,17), 64, 0, stream>>>(eWhh, u, v, Wenc);
  prep_wdec<<<dim3(128,33), 64, 0, stream>>>(dWih, dWhh, bd, Wdec);
  prep_wqfm<<<dim3(32,17),  64, 0, stream>>>(Wqk_t, bqk, Wqf);

  // zero barrier flags/canaries (after prep_wqfm consumed Wqk_t)
  hipMemsetAsync(encFlg, 0, 200704, stream);

  f16* hbuf[2] = {hb0, hb1};

  // ---- encoder: persistent (coop launch for residency guarantee), fallback ----
  {
    void* eargs[9] = { (void*)&hb0, (void*)&hb1, (void*)&cb, (void*)&Wenc,
                       (void*)&enc_in, (void*)&hx,
                       (void*)&encFlg, (void*)&encErr, (void*)&encCan };
    hipError_t ce = hipLaunchCooperativeKernel((const void*)enc_persist,
                                               dim3(8,32), dim3(256), eargs, 0, stream);
    if(ce != hipSuccess){
      for(int t=0;t<SS;t++){
        enc_step<<<dim3(8,32), 256, 0, stream>>>(hbuf[t&1], hbuf[(t+1)&1], cb,
                                                 Wenc, enc_in, hx, t);
      }
    }
  }

  // ---- decoder: persistent (coop launch), fallback ----
  {
    void* dargs[12] = { (void*)&hb0, (void*)&hb1, (void*)&cb, (void*)&ctx,
                        (void*)&Wdec, (void*)&Wqf, (void*)&hx, (void*)&qt,
                        (void*)&hdec, (void*)&decFlg, (void*)&decErr, (void*)&decCan };
    hipError_t cd = hipLaunchCooperativeKernel((const void*)dec_persist,
                                               dim3(256), dim3(256), dargs, 0, stream);
    if(cd != hipSuccess){
      for(int t=0;t<TT;t++){
        qproj   <<<dim3(8,8),  256, 0, stream>>>(hbuf[t&1], Wqf, qt);
        attn    <<<256, 256, 0, stream>>>(qt, hx, ctx);
        dec_step<<<dim3(16,16),256, 0, stream>>>(hbuf[t&1], hbuf[(t+1)&1], cb, ctx,
                                                 Wdec, hdec, t);
      }
    }
  }

  final_out<<<TT, 256, 0, stream>>>(hdec, outW, outb, (float*)d_out);
}

// Round 8
// 10098.181 us; speedup vs baseline: 1.2386x; 1.0131x over previous
//
#include <hip/hip_runtime.h>
#include <hip/hip_bf16.h>
#include <cstdint>
#include <cstddef>

#define BB   256   // batch
#define SS   512   // encoder seq len
#define RDIM 128   // embed dim
#define HH   512   // hidden
#define TT   96    // decoder steps

typedef unsigned int u32;
typedef _Float16 f16;
typedef __attribute__((ext_vector_type(8))) _Float16 f16x8;
typedef __attribute__((ext_vector_type(4))) float f32x4;

__device__ __forceinline__ float sigm(float x){ return 1.0f/(1.0f+__expf(-x)); }
__device__ __forceinline__ float tanh_f(float x){ return 1.0f - 2.0f/(__expf(2.0f*x)+1.0f); }
__device__ __forceinline__ float2 cvt2(u32 x){
  union { u32 u; f16 h[2]; } t; t.u = x;
  return make_float2((float)t.h[0], (float)t.h[1]);
}

__device__ __forceinline__ void fence_rel(){ __builtin_amdgcn_fence(__ATOMIC_RELEASE, "agent"); }
__device__ __forceinline__ void fence_acq(){ __builtin_amdgcn_fence(__ATOMIC_ACQUIRE, "agent"); }

// L1-bypassing dword load (agent-scope relaxed atomic -> sc0, reads L2/IC).
__device__ __forceinline__ u32 ld_sc0(const u32* p){
  return __hip_atomic_load((u32*)p, __ATOMIC_RELAXED, __HIP_MEMORY_SCOPE_AGENT);
}
__device__ __forceinline__ uint4 ld4_sc0(const u32* p){
  return make_uint4(ld_sc0(p), ld_sc0(p+1), ld_sc0(p+2), ld_sc0(p+3));
}

// async global -> LDS, 16B per lane; LDS dest = wave-uniform base + lane*16
__device__ __forceinline__ void gload16(const void* g, void* l){
  __builtin_amdgcn_global_load_lds(
      (const __attribute__((address_space(1))) void*)g,
      (__attribute__((address_space(3))) void*)l, 16, 0, 0);
}

#define SPIN_CAP 50000   // escape hatch; legit waits are << this

// 32-block flag barrier: each block stores gen to its own 128B-spaced slot;
// 32 threads poll the 32 slots in parallel (no RMW serialization).
// slow=1 adds R3-proven agent fences for cross-XCD correctness.
__device__ __forceinline__ void bar32f(u32* flags, int slot, u32 gen, int slow){
  __syncthreads();                 // all waves' stores drained (vmcnt 0)
  if(threadIdx.x == 0){
    if(slow) fence_rel();
    __hip_atomic_store(&flags[slot*32], gen, __ATOMIC_RELAXED, __HIP_MEMORY_SCOPE_AGENT);
  }
  if(threadIdx.x < 32){
    int spins = 0;
    while(__hip_atomic_load(&flags[threadIdx.x*32], __ATOMIC_RELAXED, __HIP_MEMORY_SCOPE_AGENT) < gen){
      __builtin_amdgcn_s_sleep(2);
      if(++spins > SPIN_CAP) break;
    }
  }
  __syncthreads();
  if(slow){
    if(threadIdx.x == 0) fence_acq();
    __syncthreads();
  }
}

// Fence-free-mode validity probe (2 rounds of canary store / fast barrier /
// sc0 peer read). Any stale read -> domain err flag -> slow barriers.
// Consumes generations 1..4; caller continues from gen=4.
__device__ __forceinline__ int probe32f(u32* flags, int slot, u32* can, u32* flg,
                                        int id, int g, int tid){
  __shared__ u32 okf;
  u32 gen = 0;
  #pragma unroll
  for(int r=0;r<2;r++){
    u32 tag = r ? 0x5A5A0000u : 0xA5A50000u;
    if(tid==0) can[(size_t)id*64 + r] = tag + (u32)id;   // plain store -> L2
    ++gen; bar32f(flags, slot, gen, 0);
    if(tid==0) okf = 1u;
    __syncthreads();
    if(tid < 32){
      int mid = g + 8*tid;                                // domain members
      u32 v = ld_sc0(can + (size_t)mid*64 + r);
      if(v != tag + (u32)mid) okf = 0u;                   // benign race (1->0)
    }
    __syncthreads();
    if(tid==0 && okf==0u)
      __hip_atomic_store(flg, 1u, __ATOMIC_RELAXED, __HIP_MEMORY_SCOPE_AGENT);
    ++gen; bar32f(flags, slot, gen, 0);
  }
  return (int)__hip_atomic_load(flg, __ATOMIC_RELAXED, __HIP_MEMORY_SCOPE_AGENT);
}

// ---------------------------------------------------------------------------
// Prep kernels (unchanged, r0-verified)
// ---------------------------------------------------------------------------

__global__ void prep_uv(const float* __restrict__ Wih, const float* __restrict__ embW,
                        const float* __restrict__ embB, const float* __restrict__ bih,
                        const float* __restrict__ bhh, const float* __restrict__ dbih,
                        const float* __restrict__ dbhh,
                        float* __restrict__ u, float* __restrict__ v, float* __restrict__ bd){
  int n = blockIdx.x*256 + threadIdx.x;   // 0..2047
  const float* row = Wih + (size_t)n*RDIM;
  float su = 0.f, sv = 0.f;
  for(int r=0;r<RDIM;r++){ float w = row[r]; su += w*embW[r]; sv += w*embB[r]; }
  u[n] = su;
  v[n] = sv + bih[n] + bhh[n];
  bd[n] = dbih[n] + dbhh[n];
}

__global__ void prep_wqk(const float* __restrict__ Wq, const float* __restrict__ Wk,
                         float* __restrict__ Wqk_t){
  __shared__ float wkc[HH];
  int n = blockIdx.x;
  for(int i=threadIdx.x;i<HH;i+=256) wkc[i] = Wk[(size_t)i*HH + n];
  __syncthreads();
  for(int a=threadIdx.x;a<HH;a+=256){
    float s = 0.f;
    for(int hp=0;hp<HH;hp++) s += Wq[(size_t)hp*HH + a]*wkc[hp];
    Wqk_t[(size_t)n*HH + a] = s;
  }
}

__global__ void prep_bqk(const float* __restrict__ bq, const float* __restrict__ Wk,
                         float* __restrict__ bqk){
  int n = blockIdx.x*256 + threadIdx.x;
  float s = 0.f;
  for(int hp=0;hp<HH;hp++) s += bq[hp]*Wk[(size_t)hp*HH + n];
  bqk[n] = s;
}

__global__ void prep_wenc(const float* __restrict__ Whh, const float* __restrict__ u,
                          const float* __restrict__ v, f16* __restrict__ Wfm){
  int nt = blockIdx.x, kk = blockIdx.y, L = threadIdx.x;
  int jb = nt>>2, ct = nt&3;
  int n = ct*HH + jb*16 + (L&15);
  int q = L>>4;
  union { f16 h[8]; uint4 u4; } z;
  if(kk < 16){
    const float* src = Whh + (size_t)n*HH + kk*32 + q*8;
    #pragma unroll
    for(int j=0;j<8;j++) z.h[j] = (f16)src[j];
  } else {
    #pragma unroll
    for(int j=0;j<8;j++) z.h[j] = (f16)0.0f;
    if(q==0){ z.h[0] = (f16)u[n]; z.h[1] = (f16)v[n]; }
  }
  *(uint4*)(Wfm + (((size_t)nt*17 + kk)*64 + L)*8) = z.u4;
}

__global__ void prep_wdec(const float* __restrict__ dWih, const float* __restrict__ dWhh,
                          const float* __restrict__ bd, f16* __restrict__ Wfm){
  int nt = blockIdx.x, kk = blockIdx.y, L = threadIdx.x;
  int jb = nt>>3, ct = nt&7;
  int n = (ct>>1)*HH + jb*32 + (ct&1)*16 + (L&15);
  int q = L>>4;
  union { f16 h[8]; uint4 u4; } z;
  if(kk < 32){
    int k0 = kk*32 + q*8;
    #pragma unroll
    for(int j=0;j<8;j++){
      float wv = dWih[(size_t)n*1024 + k0 + j];
      if(k0 + j < HH) wv += dWhh[(size_t)n*HH + k0 + j];
      z.h[j] = (f16)wv;
    }
  } else {
    #pragma unroll
    for(int j=0;j<8;j++) z.h[j] = (f16)0.0f;
    if(q==0) z.h[0] = (f16)bd[n];
  }
  *(uint4*)(Wfm + (((size_t)nt*33 + kk)*64 + L)*8) = z.u4;
}

__global__ void prep_wqfm(const float* __restrict__ Wqk_t, const float* __restrict__ bqk,
                          f16* __restrict__ Wfm){
  int nt = blockIdx.x, kk = blockIdx.y, L = threadIdx.x;
  int n = nt*16 + (L&15);
  int q = L>>4;
  union { f16 h[8]; uint4 u4; } z;
  if(kk < 16){
    const float* src = Wqk_t + (size_t)n*HH + kk*32 + q*8;
    #pragma unroll
    for(int j=0;j<8;j++) z.h[j] = (f16)src[j];
  } else {
    #pragma unroll
    for(int j=0;j<8;j++) z.h[j] = (f16)0.0f;
    if(q==0) z.h[0] = (f16)bqk[n];
  }
  *(uint4*)(Wfm + (((size_t)nt*17 + kk)*64 + L)*8) = z.u4;
}

// ---------------------------------------------------------------------------
// r0-VERIFIED standalone step kernels (fallback path)
// ---------------------------------------------------------------------------
#define STR 552   // LDS row stride in f16 (544 data + 8 pad)

__launch_bounds__(256)
__global__ void enc_step(const f16* __restrict__ hin, f16* __restrict__ hout,
                         float* __restrict__ cbuf, const f16* __restrict__ Wfm,
                         const float* __restrict__ einp, f16* __restrict__ hx, int t){
  __shared__ f16 hsm[32*STR];
  __shared__ float gt[64][33];
  const int tid = threadIdx.x;
  const int b0 = blockIdx.x*32, jb = blockIdx.y;

  {
    int row = tid>>3, c0 = tid&7;
    const uint4* src = (const uint4*)(hin + (size_t)(b0+row)*HH);
    uint4* drow = (uint4*)(hsm + row*STR);
    #pragma unroll
    for(int i=0;i<8;i++) drow[c0 + 8*i] = src[c0 + 8*i];
  }
  if(tid < 128){
    int row = tid>>2, pc = tid&3;
    union { f16 h[8]; uint4 u4; } z;
    #pragma unroll
    for(int j=0;j<8;j++) z.h[j] = (f16)0.0f;
    if(pc==0){ z.h[0] = (f16)einp[(size_t)(b0+row)*SS + t]; z.h[1] = (f16)1.0f; }
    *((uint4*)(hsm + row*STR) + 64 + pc) = z.u4;
  }
  __syncthreads();

  const int lane = tid & 63, w = tid>>6;
  const int rt = w & 1, ctb = (w>>1)*2;
  const int m = lane & 15, q = lane>>4;
  f32x4 acc0 = {0.f,0.f,0.f,0.f}, acc1 = {0.f,0.f,0.f,0.f};
  const f16* arow = hsm + (rt*16 + m)*STR + q*8;
  const f16x8* bp0 = (const f16x8*)Wfm + ((size_t)(jb*4+ctb  )*17)*64 + lane;
  const f16x8* bp1 = (const f16x8*)Wfm + ((size_t)(jb*4+ctb+1)*17)*64 + lane;
  #pragma unroll
  for(int kk=0;kk<17;kk++){
    f16x8 a  = *(const f16x8*)(arow + kk*32);
    f16x8 b0 = bp0[kk*64];
    f16x8 b1 = bp1[kk*64];
    acc0 = __builtin_amdgcn_mfma_f32_16x16x32_f16(a, b0, acc0, 0,0,0);
    acc1 = __builtin_amdgcn_mfma_f32_16x16x32_f16(a, b1, acc1, 0,0,0);
  }
  #pragma unroll
  for(int r=0;r<4;r++){
    gt[(ctb  )*16 + m][rt*16 + q*4 + r] = acc0[r];   // C/D: col=lane&15, row=4q+r
    gt[(ctb+1)*16 + m][rt*16 + q*4 + r] = acc1[r];
  }
  __syncthreads();

  #pragma unroll
  for(int qq=0;qq<2;qq++){
    int idx = tid + qq*256;
    int jc = idx & 15, rr = idx >> 4;
    float gi = gt[jc][rr];
    float gf = gt[16+jc][rr];
    float gg = gt[32+jc][rr];
    float go = gt[48+jc][rr];
    int b = b0 + rr, j = jb*16 + jc;
    size_t ci = (size_t)b*HH + j;
    float cv = sigm(gf)*cbuf[ci] + sigm(gi)*tanh_f(gg);
    cbuf[ci] = cv;
    float hv = sigm(go)*tanh_f(cv);
    hout[ci] = (f16)hv;
    hx[((size_t)b*SS + t)*HH + j] = (f16)hv;
  }
}

__launch_bounds__(256)
__global__ void qproj(const f16* __restrict__ hin, const f16* __restrict__ Wfm,
                      float* __restrict__ qt){
  __shared__ f16 hsm[32*STR];
  const int tid = threadIdx.x;
  const int b0 = blockIdx.x*32, jb = blockIdx.y;
  {
    int row = tid>>3, c0 = tid&7;
    const uint4* src = (const uint4*)(hin + (size_t)(b0+row)*HH);
    uint4* drow = (uint4*)(hsm + row*STR);
    #pragma unroll
    for(int i=0;i<8;i++) drow[c0 + 8*i] = src[c0 + 8*i];
  }
  if(tid < 128){
    int row = tid>>2, pc = tid&3;
    union { f16 h[8]; uint4 u4; } z;
    #pragma unroll
    for(int j=0;j<8;j++) z.h[j] = (f16)0.0f;
    if(pc==0) z.h[0] = (f16)1.0f;
    *((uint4*)(hsm + row*STR) + 64 + pc) = z.u4;
  }
  __syncthreads();

  const int lane = tid & 63, w = tid>>6;
  const int rt = w & 1, ctb = (w>>1)*2;
  const int m = lane & 15, q = lane>>4;
  f32x4 acc0 = {0.f,0.f,0.f,0.f}, acc1 = {0.f,0.f,0.f,0.f};
  const f16* arow = hsm + (rt*16 + m)*STR + q*8;
  const f16x8* bp0 = (const f16x8*)Wfm + ((size_t)(jb*4+ctb  )*17)*64 + lane;
  const f16x8* bp1 = (const f16x8*)Wfm + ((size_t)(jb*4+ctb+1)*17)*64 + lane;
  #pragma unroll
  for(int kk=0;kk<17;kk++){
    f16x8 a  = *(const f16x8*)(arow + kk*32);
    f16x8 b0 = bp0[kk*64];
    f16x8 b1 = bp1[kk*64];
    acc0 = __builtin_amdgcn_mfma_f32_16x16x32_f16(a, b0, acc0, 0,0,0);
    acc1 = __builtin_amdgcn_mfma_f32_16x16x32_f16(a, b1, acc1, 0,0,0);
  }
  #pragma unroll
  for(int r=0;r<4;r++){
    int b = b0 + rt*16 + q*4 + r;
    qt[(size_t)b*HH + jb*64 + (ctb  )*16 + m] = acc0[r];
    qt[(size_t)b*HH + jb*64 + (ctb+1)*16 + m] = acc1[r];
  }
}

__launch_bounds__(256)
__global__ void attn(const float* __restrict__ qt, const f16* __restrict__ hx,
                     f16* __restrict__ ctx){
  __shared__ unsigned short xs[32][520];
  __shared__ float sc[32];
  const int b = blockIdx.x, tid = threadIdx.x;
  const int seg = tid & 7;
  const int sp  = tid >> 3;

  float qreg[64];
  {
    const float4* qv = (const float4*)(qt + (size_t)b*HH + seg*64);
    #pragma unroll
    for(int i=0;i<16;i++){
      float4 v4 = qv[i];
      qreg[i*4+0]=v4.x; qreg[i*4+1]=v4.y; qreg[i*4+2]=v4.z; qreg[i*4+3]=v4.w;
    }
  }

  float m = -1e30f, l = 0.f, a0 = 0.f, a1 = 0.f;
  const uint4* src = (const uint4*)(hx + (size_t)b*SS*HH);

  for(int tile=0; tile<16; ++tile){
    __syncthreads();
    const uint4* tsrc = src + (size_t)tile*2048;
    #pragma unroll
    for(int kk=0;kk<8;kk++){
      uint4 vv = tsrc[kk*256 + tid];
      int e  = (kk*256 + tid)*8;
      int ss = e >> 9, hh = e & 511;
      *(uint4*)&xs[ss][hh] = vv;
    }
    __syncthreads();

    float p = 0.f;
    const uint4* xrow = (const uint4*)&xs[sp][seg*64];
    #pragma unroll
    for(int i=0;i<8;i++){
      uint4 vv = xrow[i];
      float2 t0 = cvt2(vv.x), t1 = cvt2(vv.y), t2 = cvt2(vv.z), t3 = cvt2(vv.w);
      p = fmaf(qreg[i*8+0], t0.x, p);
      p = fmaf(qreg[i*8+1], t0.y, p);
      p = fmaf(qreg[i*8+2], t1.x, p);
      p = fmaf(qreg[i*8+3], t1.y, p);
      p = fmaf(qreg[i*8+4], t2.x, p);
      p = fmaf(qreg[i*8+5], t2.y, p);
      p = fmaf(qreg[i*8+6], t3.x, p);
      p = fmaf(qreg[i*8+7], t3.y, p);
    }
    p += __shfl_xor(p, 1);
    p += __shfl_xor(p, 2);
    p += __shfl_xor(p, 4);
    if(seg == 0) sc[sp] = p;
    __syncthreads();

    float tmax = -1e30f;
    #pragma unroll
    for(int s2=0;s2<32;s2++) tmax = fmaxf(tmax, sc[s2]);
    float mnew  = fmaxf(m, tmax);
    float alpha = __expf(m - mnew);
    a0 *= alpha; a1 *= alpha; l *= alpha;
    #pragma unroll 4
    for(int s2=0;s2<32;s2++){
      float pv = __expf(sc[s2] - mnew);
      l += pv;
      u32 xv = *(const u32*)&xs[s2][2*tid];
      float2 xf = cvt2(xv);
      a0 = fmaf(pv, xf.x, a0);
      a1 = fmaf(pv, xf.y, a1);
    }
    m = mnew;
  }
  float inv = 1.0f/l;
  union { u32 u; f16 h[2]; } pk;
  pk.h[0] = (f16)(a0*inv); pk.h[1] = (f16)(a1*inv);
  *(u32*)(ctx + (size_t)b*HH + 2*tid) = pk.u;
}

#define STRD 1064  // 1056 data + 8 pad (2128B)

__launch_bounds__(256)
__global__ void dec_step(const f16* __restrict__ hin, f16* __restrict__ hout,
                         float* __restrict__ cbuf, const f16* __restrict__ ctxv,
                         const f16* __restrict__ Wfm, f16* __restrict__ hdec, int t){
  __shared__ f16 hsm[16*STRD];
  __shared__ float gt[128][17];
  const int tid = threadIdx.x;
  const int b0 = blockIdx.x*16, jb = blockIdx.y;

  {
    int row = tid>>4, c0 = tid&15;
    const uint4* srch = (const uint4*)(hin  + (size_t)(b0+row)*HH);
    const uint4* srcc = (const uint4*)(ctxv + (size_t)(b0+row)*HH);
    uint4* drow = (uint4*)(hsm + row*STRD);
    #pragma unroll
    for(int i=0;i<8;i++){
      int c = c0 + 16*i;
      drow[c] = (c < 64) ? srch[c] : srcc[c-64];
    }
  }
  if(tid < 64){
    int row = tid>>2, pc = tid&3;
    union { f16 h[8]; uint4 u4; } z;
    #pragma unroll
    for(int j=0;j<8;j++) z.h[j] = (f16)0.0f;
    if(pc==0) z.h[0] = (f16)1.0f;
    *((uint4*)(hsm + row*STRD) + 128 + pc) = z.u4;
  }
  __syncthreads();

  const int lane = tid & 63, w = tid>>6;
  const int ctb = w*2;
  const int m = lane & 15, q = lane>>4;
  f32x4 acc0 = {0.f,0.f,0.f,0.f}, acc1 = {0.f,0.f,0.f,0.f};
  const f16* arow = hsm + m*STRD + q*8;
  const f16x8* bp0 = (const f16x8*)Wfm + ((size_t)(jb*8+ctb  )*33)*64 + lane;
  const f16x8* bp1 = (const f16x8*)Wfm + ((size_t)(jb*8+ctb+1)*33)*64 + lane;
  #pragma unroll
  for(int kk=0;kk<33;kk++){
    f16x8 a  = *(const f16x8*)(arow + kk*32);
    f16x8 b0 = bp0[kk*64];
    f16x8 b1 = bp1[kk*64];
    acc0 = __builtin_amdgcn_mfma_f32_16x16x32_f16(a, b0, acc0, 0,0,0);
    acc1 = __builtin_amdgcn_mfma_f32_16x16x32_f16(a, b1, acc1, 0,0,0);
  }
  #pragma unroll
  for(int r=0;r<4;r++){
    gt[(ctb  )*16 + m][q*4 + r] = acc0[r];
    gt[(ctb+1)*16 + m][q*4 + r] = acc1[r];
  }
  __syncthreads();

  #pragma unroll
  for(int qq=0;qq<2;qq++){
    int idx = tid + qq*256;
    int jc = idx & 31, rr = idx >> 5;    // jc 0..31, rr 0..15
    float gi = gt[jc][rr];
    float gf = gt[32+jc][rr];
    float gg = gt[64+jc][rr];
    float go = gt[96+jc][rr];
    int b = b0 + rr, j = jb*32 + jc;
    size_t ci = (size_t)b*HH + j;
    float cv = sigm(gf)*cbuf[ci] + sigm(gi)*tanh_f(gg);
    cbuf[ci] = cv;
    float hv = sigm(go)*tanh_f(cv);
    hout[ci] = (f16)hv;
    hdec[((size_t)t*BB + b)*HH + j] = (f16)hv;
  }
}

// ---------------------------------------------------------------------------
// Persistent encoder: grid (8,32); domain = blockIdx.x. Flag barrier.
// ---------------------------------------------------------------------------
__launch_bounds__(256, 1)
__global__ void enc_persist(f16* __restrict__ hA, f16* __restrict__ hB,
                            float* __restrict__ cbuf, const f16* __restrict__ Wfm,
                            const float* __restrict__ einp, f16* __restrict__ hx,
                            u32* __restrict__ flg8, u32* __restrict__ err8,
                            u32* __restrict__ can){
  __shared__ f16 hsm[32*STR];
  __shared__ float gt[64][33];
  const int tid = threadIdx.x;
  const int bx = blockIdx.x, jb = blockIdx.y;
  const int id = bx + 8*jb;          // linear (x-fastest)
  const int b0 = bx*32;
  const int lane = tid & 63, w = tid>>6;
  const int rt = w & 1, ctb = (w>>1)*2;
  const int m = lane & 15, q = lane>>4;

  // weights -> registers (loop-invariant, statically indexed)
  f16x8 bf0[17], bf1[17];
  {
    const f16x8* bp0 = (const f16x8*)Wfm + ((size_t)(jb*4+ctb  )*17)*64 + lane;
    const f16x8* bp1 = (const f16x8*)Wfm + ((size_t)(jb*4+ctb+1)*17)*64 + lane;
    #pragma unroll
    for(int kk=0;kk<17;kk++){ bf0[kk] = bp0[kk*64]; bf1[kk] = bp1[kk*64]; }
  }
  float creg[2] = {0.f, 0.f};
  u32* flags = flg8 + bx*1024;       // 32 slots x 128B per domain
  u32* err   = err8 + bx*64;

  const int slow = probe32f(flags, jb, can, err, id, bx, tid);
  u32 gen = 4;

  const f16* hin = hA; f16* hout = hB;
  for(int t=0;t<SS;t++){
    {
      int row = tid>>3, c0 = tid&7;
      const u32* s32 = (const u32*)(hin + (size_t)(b0+row)*HH);
      u32* d32 = (u32*)(hsm + row*STR);
      #pragma unroll
      for(int i=0;i<8;i++){
        int ci = (c0 + 8*i)*4;
        *(uint4*)(d32 + ci) = ld4_sc0(s32 + ci);    // L1-bypass: cross-block data
      }
    }
    if(tid < 128){
      int row = tid>>2, pc = tid&3;
      union { f16 h[8]; uint4 u4; } z;
      #pragma unroll
      for(int j=0;j<8;j++) z.h[j] = (f16)0.0f;
      if(pc==0){ z.h[0] = (f16)einp[(size_t)(b0+row)*SS + t]; z.h[1] = (f16)1.0f; }
      *((uint4*)(hsm + row*STR) + 64 + pc) = z.u4;
    }
    __syncthreads();

    f32x4 acc0 = {0.f,0.f,0.f,0.f}, acc1 = {0.f,0.f,0.f,0.f};
    const f16* arow = hsm + (rt*16 + m)*STR + q*8;
    #pragma unroll
    for(int kk=0;kk<17;kk++){
      f16x8 a = *(const f16x8*)(arow + kk*32);
      acc0 = __builtin_amdgcn_mfma_f32_16x16x32_f16(a, bf0[kk], acc0, 0,0,0);
      acc1 = __builtin_amdgcn_mfma_f32_16x16x32_f16(a, bf1[kk], acc1, 0,0,0);
    }
    #pragma unroll
    for(int r=0;r<4;r++){
      gt[(ctb  )*16 + m][rt*16 + q*4 + r] = acc0[r];   // C/D: col=lane&15, row=4q+r
      gt[(ctb+1)*16 + m][rt*16 + q*4 + r] = acc1[r];
    }
    __syncthreads();

    #pragma unroll
    for(int qq=0;qq<2;qq++){
      int idx = tid + qq*256;
      int jc = idx & 15, rr = idx >> 4;
      float gi = gt[jc][rr];
      float gf = gt[16+jc][rr];
      float gg = gt[32+jc][rr];
      float go = gt[48+jc][rr];
      int b = b0 + rr, j = jb*16 + jc;
      float cv = sigm(gf)*creg[qq] + sigm(gi)*tanh_f(gg);
      creg[qq] = cv;
      float hv = sigm(go)*tanh_f(cv);
      hout[(size_t)b*HH + j] = (f16)hv;
      hx[((size_t)b*SS + t)*HH + j] = (f16)hv;
      if(t == SS-1) cbuf[(size_t)b*HH + j] = cv;   // handoff c_N to decoder
    }
    if(t != SS-1){ ++gen; bar32f(flags, jb, gen, slow); }
    const f16* tmp = hin; hin = hout; hout = (f16*)tmp;
  }
}

// ---------------------------------------------------------------------------
// Persistent decoder: grid 256; domain g = id&7. Flag barriers.
// attn: STAGGERED tile order (block-specific start -> decorrelates the
// grid-wide load bursts the lockstep barriers create) + 4-buffer
// global_load_lds pipeline with 3-deep lookahead (counted vmcnt(16)).
// LDS: xs[4] = 133,120 B; hsmq/hsmd overlay xs[2..3] (dead during qproj/LSTM).
// ---------------------------------------------------------------------------
#define XTB 33280            // one attn tile buffer: 32 rows x 520 shorts
#define SMEMB (4*XTB)        // 133,120

__launch_bounds__(256, 1)
__global__ void dec_persist(f16* __restrict__ hA, f16* __restrict__ hB,
                            float* __restrict__ cbuf, f16* __restrict__ ctx,
                            const f16* __restrict__ Wdec, const f16* __restrict__ Wqf,
                            const f16* __restrict__ hx, float* __restrict__ qt,
                            f16* __restrict__ hdec, u32* __restrict__ flg8,
                            u32* __restrict__ err8, u32* __restrict__ can){
  __shared__ __align__(16) char smem[SMEMB];
  __shared__ __align__(16) float gtd[128][17];   // phase-3 gates; qsm overlay in phase 2
  __shared__ float sc[32];

  const int tid = threadIdx.x;
  const int id  = blockIdx.x;
  const int g = id & 7, k = id >> 3;
  const int lane = tid & 63, w = tid>>6;

  u32* flags = flg8 + g*1024;
  u32* err   = err8 + g*64;
  const int slow = probe32f(flags, k, can, err, id, g, tid);
  u32 gen = 4;

  // decoder cell state -> registers (ownership = phase-3 role, fixed)
  const int b0d = g*32 + ((k & 16) ? 16 : 0);
  const int jbd = k & 15;
  float creg[2];
  #pragma unroll
  for(int qq=0;qq<2;qq++){
    int idx = tid + qq*256;
    int jc = idx & 31, rr = idx >> 5;
    creg[qq] = cbuf[(size_t)(b0d+rr)*HH + (jbd*32 + jc)];
  }

  const int batt = g*32 + k;                       // attn batch for this block
  const char* hxb = (const char*)(hx + (size_t)batt*SS*HH);
  const int st = (id*5) & 15;                      // staggered tile start

  for(int t=0;t<TT;t++){
    const f16* hin = (t&1) ? hB : hA;
    f16*       hout= (t&1) ? hA : hB;

    // -------- issue attn tiles st, st+1 (bufs 0,1) — fly under qproj --------
    {
      #pragma unroll
      for(int i=0;i<2;++i){
        int pt = (st + i) & 15;
        char* dst = smem + (size_t)i*XTB;
        const char* srcb = hxb + (size_t)pt*32768 + (size_t)(w*8)*1024 + (size_t)lane*16;
        #pragma unroll
        for(int r=0;r<8;r++)
          gload16(srcb + (size_t)r*1024, dst + (size_t)(w*8+r)*1040);
      }
    }

    // ---------------- phase 1: qproj (k<8) ----------------
    if(k < 8){
      f16* hsmq = (f16*)(smem + 2*XTB);
      const int b0 = g*32, jbq = k;
      {
        int row = tid>>3, c0 = tid&7;
        const u32* s32 = (const u32*)(hin + (size_t)(b0+row)*HH);
        u32* d32 = (u32*)(hsmq + row*STR);
        #pragma unroll
        for(int i=0;i<8;i++){
          int ci = (c0 + 8*i)*4;
          *(uint4*)(d32 + ci) = ld4_sc0(s32 + ci);
        }
      }
      if(tid < 128){
        int row = tid>>2, pc = tid&3;
        union { f16 h[8]; uint4 u4; } z;
        #pragma unroll
        for(int j=0;j<8;j++) z.h[j] = (f16)0.0f;
        if(pc==0) z.h[0] = (f16)1.0f;
        *((uint4*)(hsmq + row*STR) + 64 + pc) = z.u4;
      }
      __syncthreads();
      const int rt = w & 1, ctb = (w>>1)*2;
      const int mm = lane & 15, q = lane>>4;
      f32x4 acc0 = {0.f,0.f,0.f,0.f}, acc1 = {0.f,0.f,0.f,0.f};
      const f16* arow = hsmq + (rt*16 + mm)*STR + q*8;
      const f16x8* bp0 = (const f16x8*)Wqf + ((size_t)(jbq*4+ctb  )*17)*64 + lane;
      const f16x8* bp1 = (const f16x8*)Wqf + ((size_t)(jbq*4+ctb+1)*17)*64 + lane;
      #pragma unroll
      for(int kk=0;kk<17;kk++){
        f16x8 a  = *(const f16x8*)(arow + kk*32);
        acc0 = __builtin_amdgcn_mfma_f32_16x16x32_f16(a, bp0[kk*64], acc0, 0,0,0);
        acc1 = __builtin_amdgcn_mfma_f32_16x16x32_f16(a, bp1[kk*64], acc1, 0,0,0);
      }
      #pragma unroll
      for(int r=0;r<4;r++){
        int b = b0 + rt*16 + q*4 + r;
        qt[(size_t)b*HH + jbq*64 + (ctb  )*16 + mm] = acc0[r];
        qt[(size_t)b*HH + jbq*64 + (ctb+1)*16 + mm] = acc1[r];
      }
    }
    ++gen; bar32f(flags, k, gen, slow);

    // ---------------- phase 2: attn (b = batt), staggered + pipelined ----------------
    {
      const int seg = tid & 7, sp = tid >> 3;
      float* qsm = &gtd[0][0];               // [8][68] padded floats

      // stage q to LDS (sc0 dwords); syncthreads drains bufs 0,1 (issued long ago)
      {
        int i2 = tid*2;
        u32 q0 = ld_sc0((const u32*)qt + (size_t)batt*HH + i2);
        u32 q1 = ld_sc0((const u32*)qt + (size_t)batt*HH + i2 + 1);
        qsm[((i2  )>>6)*68 + ((i2  )&63)] = __uint_as_float(q0);
        qsm[((i2+1)>>6)*68 + ((i2+1)&63)] = __uint_as_float(q1);
      }
      __syncthreads();                       // qsm visible; vmcnt drained to 0

      // issue tile i=2 into buf 2 (hsmq region now dead)
      {
        int pt = (st + 2) & 15;
        char* dst = smem + 2*XTB;
        const char* srcb = hxb + (size_t)pt*32768 + (size_t)(w*8)*1024 + (size_t)lane*16;
        #pragma unroll
        for(int r=0;r<8;r++)
          gload16(srcb + (size_t)r*1024, dst + (size_t)(w*8+r)*1040);
      }

      float mx = -1e30f, l = 0.f, a0 = 0.f, a1 = 0.f;

      for(int i=0; i<16; ++i){
        unsigned short (*xb)[520] =
            (unsigned short(*)[520])(smem + (size_t)(i&3)*XTB);
        // wait this tile's loads done (counted; keep lookahead in flight)
        if(i <= 13)      asm volatile("s_waitcnt vmcnt(16)" ::: "memory");
        else if(i == 14) asm volatile("s_waitcnt vmcnt(8)"  ::: "memory");
        else             asm volatile("s_waitcnt vmcnt(0)"  ::: "memory");
        __builtin_amdgcn_sched_barrier(0);
        __builtin_amdgcn_s_barrier();        // raw: does NOT drain vmcnt
        __builtin_amdgcn_sched_barrier(0);
        // issue tile i+3 into buf (i+3)&3 (freed: all waves past PV(i-1))
        if(i < 13){
          int pt = (st + i + 3) & 15;
          char* dst = smem + (size_t)((i+3)&3)*XTB;
          const char* srcb = hxb + (size_t)pt*32768
                           + (size_t)(w*8)*1024 + (size_t)lane*16;
          #pragma unroll
          for(int r=0;r<8;r++)
            gload16(srcb + (size_t)r*1024, dst + (size_t)(w*8+r)*1040);
        }

        float p = 0.f;
        const uint4*  xrow = (const uint4*)&xb[sp][seg*64];
        const float4* qv   = (const float4*)&qsm[seg*68];
        #pragma unroll
        for(int i2=0;i2<8;i2++){
          uint4 vv = xrow[i2];
          float4 qa = qv[2*i2], qb = qv[2*i2+1];
          float2 t0 = cvt2(vv.x), t1 = cvt2(vv.y), t2 = cvt2(vv.z), t3 = cvt2(vv.w);
          p = fmaf(qa.x, t0.x, p);
          p = fmaf(qa.y, t0.y, p);
          p = fmaf(qa.z, t1.x, p);
          p = fmaf(qa.w, t1.y, p);
          p = fmaf(qb.x, t2.x, p);
          p = fmaf(qb.y, t2.y, p);
          p = fmaf(qb.z, t3.x, p);
          p = fmaf(qb.w, t3.y, p);
        }
        p += __shfl_xor(p, 1);
        p += __shfl_xor(p, 2);
        p += __shfl_xor(p, 4);
        if(seg == 0) sc[sp] = p;
        asm volatile("s_waitcnt lgkmcnt(0)" ::: "memory");
        __builtin_amdgcn_sched_barrier(0);
        __builtin_amdgcn_s_barrier();        // sc visible; vmcnt untouched
        __builtin_amdgcn_sched_barrier(0);

        float tmax = -1e30f;
        #pragma unroll
        for(int s2=0;s2<32;s2++) tmax = fmaxf(tmax, sc[s2]);
        float mnew  = fmaxf(mx, tmax);
        float alpha = __expf(mx - mnew);
        a0 *= alpha; a1 *= alpha; l *= alpha;
        #pragma unroll 4
        for(int s2=0;s2<32;s2++){
          float pv = __expf(sc[s2] - mnew);
          l += pv;
          u32 xv = *(const u32*)&xb[s2][2*tid];
          float2 xf = cvt2(xv);
          a0 = fmaf(pv, xf.x, a0);
          a1 = fmaf(pv, xf.y, a1);
        }
        mx = mnew;
      }
      float inv = 1.0f/l;
      union { u32 u; f16 h[2]; } pk;
      pk.h[0] = (f16)(a0*inv); pk.h[1] = (f16)(a1*inv);
      *(u32*)(ctx + (size_t)batt*HH + 2*tid) = pk.u;
    }
    ++gen; bar32f(flags, k, gen, slow);

    // ---------------- phase 3: decoder LSTM (chunk b0d, jbd) ----------------
    {
      f16* hsmd = (f16*)(smem + 2*XTB);
      {
        int row = tid>>4, c0 = tid&15;
        const u32* sh = (const u32*)(hin + (size_t)(b0d+row)*HH);
        const u32* sx = (const u32*)(ctx + (size_t)(b0d+row)*HH);
        u32* d32 = (u32*)(hsmd + row*STRD);
        #pragma unroll
        for(int i=0;i<8;i++){
          int c = c0 + 16*i;
          const u32* s = (c < 64) ? (sh + c*4) : (sx + (c-64)*4);
          *(uint4*)(d32 + c*4) = ld4_sc0(s);
        }
      }
      if(tid < 64){
        int row = tid>>2, pc = tid&3;
        union { f16 h[8]; uint4 u4; } z;
        #pragma unroll
        for(int j=0;j<8;j++) z.h[j] = (f16)0.0f;
        if(pc==0) z.h[0] = (f16)1.0f;
        *((uint4*)(hsmd + row*STRD) + 128 + pc) = z.u4;
      }
      __syncthreads();
      const int ctb = w*2;
      const int mm = lane & 15, q = lane>>4;
      f32x4 acc0 = {0.f,0.f,0.f,0.f}, acc1 = {0.f,0.f,0.f,0.f};
      const f16* arow = hsmd + mm*STRD + q*8;
      const f16x8* bp0 = (const f16x8*)Wdec + ((size_t)(jbd*8+ctb  )*33)*64 + lane;
      const f16x8* bp1 = (const f16x8*)Wdec + ((size_t)(jbd*8+ctb+1)*33)*64 + lane;
      #pragma unroll
      for(int kk=0;kk<33;kk++){
        f16x8 a  = *(const f16x8*)(arow + kk*32);
        acc0 = __builtin_amdgcn_mfma_f32_16x16x32_f16(a, bp0[kk*64], acc0, 0,0,0);
        acc1 = __builtin_amdgcn_mfma_f32_16x16x32_f16(a, bp1[kk*64], acc1, 0,0,0);
      }
      #pragma unroll
      for(int r=0;r<4;r++){
        gtd[(ctb  )*16 + mm][q*4 + r] = acc0[r];
        gtd[(ctb+1)*16 + mm][q*4 + r] = acc1[r];
      }
      __syncthreads();
      #pragma unroll
      for(int qq=0;qq<2;qq++){
        int idx = tid + qq*256;
        int jc = idx & 31, rr = idx >> 5;
        float gi = gtd[jc][rr];
        float gf = gtd[32+jc][rr];
        float gg = gtd[64+jc][rr];
        float go = gtd[96+jc][rr];
        int b = b0d + rr, j = jbd*32 + jc;
        float cv = sigm(gf)*creg[qq] + sigm(gi)*tanh_f(gg);
        creg[qq] = cv;
        float hv = sigm(go)*tanh_f(cv);
        hout[(size_t)b*HH + j] = (f16)hv;
        hdec[((size_t)t*BB + b)*HH + j] = (f16)hv;
      }
    }
    if(t != TT-1){ ++gen; bar32f(flags, k, gen, slow); }
  }
}

// out[b,t] = hdec[t,b,:] . out_W + out_b
__launch_bounds__(256)
__global__ void final_out(const f16* __restrict__ hdec, const float* __restrict__ outW,
                          const float* __restrict__ outb, float* __restrict__ out){
  __shared__ float w[HH];
  int t = blockIdx.x;
  for(int i=threadIdx.x;i<HH;i+=256) w[i] = outW[i];
  __syncthreads();
  int b = threadIdx.x;
  const uint4* hp = (const uint4*)(hdec + ((size_t)t*BB + b)*HH);
  float s = 0.f;
  #pragma unroll 4
  for(int j=0;j<HH/8;j++){
    uint4 hv = hp[j];
    float2 t0 = cvt2(hv.x), t1 = cvt2(hv.y), t2 = cvt2(hv.z), t3 = cvt2(hv.w);
    s = fmaf(t0.x, w[j*8+0], s); s = fmaf(t0.y, w[j*8+1], s);
    s = fmaf(t1.x, w[j*8+2], s); s = fmaf(t1.y, w[j*8+3], s);
    s = fmaf(t2.x, w[j*8+4], s); s = fmaf(t2.y, w[j*8+5], s);
    s = fmaf(t3.x, w[j*8+6], s); s = fmaf(t3.y, w[j*8+7], s);
  }
  out[(size_t)b*TT + t] = s + outb[0];
}

// ---------------------------------------------------------------------------
extern "C" void kernel_launch(void* const* d_in, const int* in_sizes, int n_in,
                              void* d_out, int out_size, void* d_ws, size_t ws_size,
                              hipStream_t stream){
  const float* enc_in = (const float*)d_in[0];
  const float* embW = (const float*)d_in[2];
  const float* embB = (const float*)d_in[3];
  const float* eWih = (const float*)d_in[4];
  const float* eWhh = (const float*)d_in[5];
  const float* ebih = (const float*)d_in[6];
  const float* ebhh = (const float*)d_in[7];
  const float* dWih = (const float*)d_in[8];
  const float* dWhh = (const float*)d_in[9];
  const float* dbih = (const float*)d_in[10];
  const float* dbhh = (const float*)d_in[11];
  const float* Wq   = (const float*)d_in[12];
  const float* bq   = (const float*)d_in[13];
  const float* Wk   = (const float*)d_in[14];
  // d_in[15]: bk — softmax-invariant, unused
  const float* outW = (const float*)d_in[16];
  const float* outb = (const float*)d_in[17];

  // ---- workspace layout (byte offsets, all 16B-aligned) ----
  char* base = (char*)d_ws;
  f16* Wenc = (f16*)(base + 0);              // 2,228,224 B
  f16* Wdec = (f16*)(base + 2228224);        // 4,325,376 B
  f16* Wqf  = (f16*)(base + 6553600);        // 557,056 B
  f16* hb0  = (f16*)(base + 7110656);        // 262,144 B
  f16* hb1  = (f16*)(base + 7372800);        // 262,144 B
  f16* ctx  = (f16*)(base + 7634944);        // 262,144 B
  f16* hdec = (f16*)(base + 7897088);        // 25,165,824 B
  f16* hx   = (f16*)(base + 33062912);       // 134,217,728 B
  float* u     = (float*)(base + 167280640); // 8,192 B
  float* v     = (float*)(base + 167288832);
  float* bd    = (float*)(base + 167297024);
  float* bqk   = (float*)(base + 167305216); // 2,048 B
  float* Wqk_t = (float*)(base + 167307264); // 1,048,576 B (dead after prep_wqfm)
  float* cb    = (float*)(base + 168355840); // 524,288 B
  float* qt    = (float*)(base + 168880128); // 524,288 B
  // barrier area overlays dead Wqk_t (live only after prep_wqfm):
  const size_t WOFF = 167307264;
  u32* encFlg = (u32*)(base + WOFF);             // 8 dom x 32 slots x 128B = 32,768
  u32* encErr = (u32*)(base + WOFF + 32768);     // 8 x 256B = 2,048
  u32* encCan = (u32*)(base + WOFF + 34816);     // 256 x 256B = 65,536
  u32* decFlg = (u32*)(base + WOFF + 100352);    // 32,768
  u32* decErr = (u32*)(base + WOFF + 133120);    // 2,048
  u32* decCan = (u32*)(base + WOFF + 135168);    // 65,536 (ends 200,704)

  hipMemsetAsync(hb0, 0, (size_t)BB*HH*sizeof(f16), stream);
  hipMemsetAsync(cb,  0, (size_t)BB*HH*sizeof(float), stream);

  prep_uv  <<<8, 256, 0, stream>>>(eWih, embW, embB, ebih, ebhh, dbih, dbhh, u, v, bd);
  prep_bqk <<<2, 256, 0, stream>>>(bq, Wk, bqk);
  prep_wqk <<<512, 256, 0, stream>>>(Wq, Wk, Wqk_t);
  prep_wenc<<<dim3(128,17), 64, 0, stream>>>(eWhh, u, v, Wenc);
  prep_wdec<<<dim3(128,33), 64, 0, stream>>>(dWih, dWhh, bd, Wdec);
  prep_wqfm<<<dim3(32,17),  64, 0, stream>>>(Wqk_t, bqk, Wqf);

  // zero barrier flags/canaries (after prep_wqfm consumed Wqk_t)
  hipMemsetAsync(encFlg, 0, 200704, stream);

  f16* hbuf[2] = {hb0, hb1};

  // ---- encoder: persistent (coop launch for residency guarantee), fallback ----
  {
    void* eargs[9] = { (void*)&hb0, (void*)&hb1, (void*)&cb, (void*)&Wenc,
                       (void*)&enc_in, (void*)&hx,
                       (void*)&encFlg, (void*)&encErr, (void*)&encCan };
    hipError_t ce = hipLaunchCooperativeKernel((const void*)enc_persist,
                                               dim3(8,32), dim3(256), eargs, 0, stream);
    if(ce != hipSuccess){
      for(int t=0;t<SS;t++){
        enc_step<<<dim3(8,32), 256, 0, stream>>>(hbuf[t&1], hbuf[(t+1)&1], cb,
                                                 Wenc, enc_in, hx, t);
      }
    }
  }

  // ---- decoder: persistent (coop launch), fallback ----
  {
    void* dargs[12] = { (void*)&hb0, (void*)&hb1, (void*)&cb, (void*)&ctx,
                        (void*)&Wdec, (void*)&Wqf, (void*)&hx, (void*)&qt,
                        (void*)&hdec, (void*)&decFlg, (void*)&decErr, (void*)&decCan };
    hipError_t cd = hipLaunchCooperativeKernel((const void*)dec_persist,
                                               dim3(256), dim3(256), dargs, 0, stream);
    if(cd != hipSuccess){
      for(int t=0;t<TT;t++){
        qproj   <<<dim3(8,8),  256, 0, stream>>>(hbuf[t&1], Wqf, qt);
        attn    <<<256, 256, 0, stream>>>(qt, hx, ctx);
        dec_step<<<dim3(16,16),256, 0, stream>>>(hbuf[t&1], hbuf[(t+1)&1], cb, ctx,
                                                 Wdec, hdec, t);
      }
    }
  }

  final_out<<<TT, 256, 0, stream>>>(hdec, outW, outb, (float*)d_out);
}